// Round 11
// baseline (507.317 us; speedup 1.0000x reference)
//
#include <hip/hip_runtime.h>
#include <stdint.h>

#define NB 4
#define NC 256
#define NCI 128
#define NN 4096

typedef __attribute__((ext_vector_type(8))) short short8;
typedef __attribute__((ext_vector_type(4))) float f32x4;

__device__ __forceinline__ float bf2f(unsigned short u) {
    union { unsigned int i; float f; } v; v.i = ((unsigned int)u) << 16; return v.f;
}
__device__ __forceinline__ unsigned short f2bf(float f) {
    union { unsigned int i; float f; } v; v.f = f;
    unsigned int b = v.i;
    b += 0x7FFFu + ((b >> 16) & 1u);   // RNE
    return (unsigned short)(b >> 16);
}

// ---------------------------------------------------------------- sentinel fill
__global__ void k_fill(float* __restrict__ p, float v, int n) {
    int i = blockIdx.x * blockDim.x + threadIdx.x;
    if (i < n) p[i] = v;
}

// ---------------------------------------------------------------- K0: weight split/convert
__global__ __launch_bounds__(256) void k_split(
    const float* __restrict__ Wt, const float* __restrict__ Wp,
    const float* __restrict__ Wg, const float* __restrict__ Wo,
    unsigned short* __restrict__ wbuf) {
    const float LOG2E = 1.4426950408889634f;
    int m = blockIdx.y;
    int i = blockIdx.x * 256 + threadIdx.x;
    if (m == 0) {
        float v = Wt[i] * LOG2E;
        unsigned short h = f2bf(v);
        wbuf[i] = h;
        wbuf[32768 + i] = f2bf(v - bf2f(h));
    } else if (m == 1) {
        float v = Wp[i];
        unsigned short h = f2bf(v);
        wbuf[65536 + i] = h;
        wbuf[98304 + i] = f2bf(v - bf2f(h));
    } else if (m == 2) {
        wbuf[131072 + i] = f2bf(Wg[i]);
    } else {
        wbuf[163840 + i] = f2bf(Wo[i]);
    }
}

// ---------------------------------------------------------------- K1: phi (hi/lo) + g projections
__global__ __launch_bounds__(256, 2) void k_qkv2(
    const float* __restrict__ x,
    const unsigned short* __restrict__ WpH, const unsigned short* __restrict__ WpL,
    const unsigned short* __restrict__ WgH,
    const float* __restrict__ bp, const float* __restrict__ bg,
    unsigned short* __restrict__ phiH, unsigned short* __restrict__ phiL,
    unsigned short* __restrict__ gout) {
    __shared__ __align__(16) unsigned short sXh[32 * 72];
    __shared__ __align__(16) unsigned short sXl[32 * 72];
    const int b = blockIdx.y, n0 = blockIdx.x * 32;
    const int tid = threadIdx.x, lane = tid & 63, wave = tid >> 6;
    const int col = lane & 15, quad = lane >> 4;
    const int wm = wave * 32;

    f32x4 accP[2][2], accG[2][2];
#pragma unroll
    for (int i = 0; i < 2; i++)
#pragma unroll
        for (int j = 0; j < 2; j++)
#pragma unroll
            for (int e = 0; e < 4; e++) { accP[i][j][e] = 0.f; accG[i][j][e] = 0.f; }

    for (int c0 = 0; c0 < NC; c0 += 64) {
        __syncthreads();
        short8 ah[2][2], al[2][2], ag[2][2];
#pragma unroll
        for (int ks = 0; ks < 2; ks++)
#pragma unroll
            for (int i = 0; i < 2; i++) {
                size_t w = (size_t)(wm + i * 16 + col) * NC + c0 + ks * 32 + quad * 8;
                ah[ks][i] = *(const short8*)&WpH[w];
                al[ks][i] = *(const short8*)&WpL[w];
                ag[ks][i] = *(const short8*)&WgH[w];
            }
        {
            int cp = tid >> 3, n4 = (tid & 7) * 4;
            const float* xp = x + ((size_t)(b * NC + c0 + 2 * cp)) * NN + n0 + n4;
            float4 a = *(const float4*)xp;
            float4 c = *(const float4*)(xp + NN);
            float av[4] = { a.x, a.y, a.z, a.w };
            float cv[4] = { c.x, c.y, c.z, c.w };
#pragma unroll
            for (int j = 0; j < 4; j++) {
                unsigned short ha = f2bf(av[j]), hc = f2bf(cv[j]);
                unsigned short la = f2bf(av[j] - bf2f(ha)), lc = f2bf(cv[j] - bf2f(hc));
                *(unsigned int*)&sXh[(n4 + j) * 72 + 2 * cp] =
                    (unsigned int)ha | ((unsigned int)hc << 16);
                *(unsigned int*)&sXl[(n4 + j) * 72 + 2 * cp] =
                    (unsigned int)la | ((unsigned int)lc << 16);
            }
        }
        __syncthreads();
#pragma unroll
        for (int ks = 0; ks < 2; ks++)
#pragma unroll
            for (int j = 0; j < 2; j++) {
                short8 bh = *(const short8*)&sXh[(j * 16 + col) * 72 + ks * 32 + quad * 8];
                short8 bl = *(const short8*)&sXl[(j * 16 + col) * 72 + ks * 32 + quad * 8];
#pragma unroll
                for (int i = 0; i < 2; i++) {
                    accP[i][j] = __builtin_amdgcn_mfma_f32_16x16x32_bf16(ah[ks][i], bh, accP[i][j], 0, 0, 0);
                    accP[i][j] = __builtin_amdgcn_mfma_f32_16x16x32_bf16(ah[ks][i], bl, accP[i][j], 0, 0, 0);
                    accP[i][j] = __builtin_amdgcn_mfma_f32_16x16x32_bf16(al[ks][i], bh, accP[i][j], 0, 0, 0);
                    accG[i][j] = __builtin_amdgcn_mfma_f32_16x16x32_bf16(ag[ks][i], bh, accG[i][j], 0, 0, 0);
                }
            }
    }
#pragma unroll
    for (int i = 0; i < 2; i++) {
        int mrow = wm + i * 16 + quad * 4;
#pragma unroll
        for (int j = 0; j < 2; j++) {
            int n = n0 + j * 16 + col;
            unsigned short h[4], l[4];
#pragma unroll
            for (int e = 0; e < 4; e++) {
                float v = accP[i][j][e] + bp[mrow + e];
                h[e] = f2bf(v);
                l[e] = f2bf(v - bf2f(h[e]));
            }
            uint2 hv, lv;
            hv.x = (unsigned int)h[0] | ((unsigned int)h[1] << 16);
            hv.y = (unsigned int)h[2] | ((unsigned int)h[3] << 16);
            lv.x = (unsigned int)l[0] | ((unsigned int)l[1] << 16);
            lv.y = (unsigned int)l[2] | ((unsigned int)l[3] << 16);
            *(uint2*)&phiH[((size_t)(b * NN + n)) * NCI + mrow] = hv;
            *(uint2*)&phiL[((size_t)(b * NN + n)) * NCI + mrow] = lv;
#pragma unroll
            for (int r = 0; r < 4; r++)
                gout[((size_t)(b * NCI + mrow + r)) * NN + n] = f2bf(accG[i][j][r] + bg[mrow + r]);
        }
    }
}

// ---------------------------------------------------------------- K2: fused attention, 16 waves
// Resubmission of R10 (audit found no defect; prior failure judged infra).
// Block: batch b, 64 queries, 256 blocks = 1/CU, 1024 threads = 4 waves/SIMD.
// 128-KEY WINDOWS with QK waves = 2qg x 8kh (theta qh/ql[2][4] in regs) so
// each phi fragment is shared by only 2 waves (was 4) -> QK LDS reads halve
// (R9 model: LDS ~84% of window cycles). PV waves = 4qv x 4cv (16q x 32c).
// Pipeline per window (2 barriers):
//   QK(w) [phi single buf] ; softmax+Pwrite(w) [P single buf]
//   [barB] PV(w) [P(w), G slot w&1] ; STORET(w+1) [phi + G slot (w+1)&1]
//   ; LOADT(w+2) [barA]
// Hazards: phi writes post-barB vs QK reads pre-barB / post-barA; P write(w+1)
// post-barA vs PV(w) reads pre-barA; G write slot != read slot. LDS 146 KB.
__global__ __launch_bounds__(1024, 4) void k_attn(
    const float* __restrict__ x,
    const unsigned short* __restrict__ WtH, const unsigned short* __restrict__ WtL,
    const float* __restrict__ bt,
    const unsigned short* __restrict__ phiH, const unsigned short* __restrict__ phiL,
    const unsigned short* __restrict__ gmat,
    const unsigned short* __restrict__ WoH, const float* __restrict__ bo,
    float* __restrict__ y) {
    const float LOG2E = 1.4426950408889634f;
    __shared__ __align__(16) char smem[149504];
    // main-loop regions
    unsigned short* sPhiH  = (unsigned short*)(smem);            // [128 k][128 ci] swz
    unsigned short* sPhiL  = (unsigned short*)(smem + 32768);    // [128 k][128 ci] swz
    unsigned short* sGbase = (unsigned short*)(smem + 65536);    // 2 x [128 c][128 k] swz
    unsigned short* sPall  = (unsigned short*)(smem + 131072);   // [64 q][128 k] swz
    float* sLi             = (float*)(smem + 147456);            // [16 waves][32 q]
    // prologue overlays (all dead before first main-loop store)
    unsigned short* sThH  = (unsigned short*)(smem);             // [64 q][128] swz
    unsigned short* sThL  = (unsigned short*)(smem + 16384);
    unsigned short* sXhA  = (unsigned short*)(smem + 32768);     // [64 n][72] linear
    unsigned short* sXlA  = (unsigned short*)(smem + 41984);
    unsigned short* sXhB  = (unsigned short*)(smem + 51200);
    unsigned short* sXlB  = (unsigned short*)(smem + 60416);
    float* sThF           = (float*)(smem + 32768);              // [64 q][128] f32 swz (after sX dead)
    // epilogue overlay
    unsigned short* sO    = (unsigned short*)(smem);             // [64 q][128] swz

    const int id = blockIdx.x;
    const int xcd = id & 7, slot = id >> 3;                      // slot 0..31
    const int b = xcd >> 1;                                      // batch pinned to 2 XCDs
    const int n0 = (slot * 2 + (xcd & 1)) * 64;

    const int tid = threadIdx.x, lane = tid & 63, wave = tid >> 6;  // wave 0..15
    const int col = lane & 15, quad = lane >> 4;
    // QK roles: 2 query-halves x 8 key-sixteenths of the 128-key window
    const int qg = wave >> 3, kh = wave & 7;
    // PV roles: 4 query-sixteenths x 4 channel-32s
    const int qv = wave & 3, cv = wave >> 2;

    // staged-window registers (128 keys: 2 uint4 per buffer per thread)
    uint4 rPh[2], rPl[2], rG[2];
    auto LOADTW = [&](int kbase) {
#pragma unroll
        for (int i = 0; i < 2; i++) {
            int j = tid + i * 1024;
            int row = j >> 4, seg = j & 15;
            size_t sp = ((size_t)(b * NN + kbase + row)) * NCI + seg * 8;
            rPh[i] = *(const uint4*)&phiH[sp];
            rPl[i] = *(const uint4*)&phiL[sp];
            rG[i]  = *(const uint4*)&gmat[((size_t)(b * NCI + row)) * NN + kbase + seg * 8];
        }
    };
    auto STORETW = [&](unsigned short* gDst) {
#pragma unroll
        for (int i = 0; i < 2; i++) {
            int j = tid + i * 1024;
            int row = j >> 4, seg = j & 15;
            int dst = row * 128 + ((seg * 8) ^ ((row & 7) << 3));
            *(uint4*)&sPhiH[dst] = rPh[i];
            *(uint4*)&sPhiL[dst] = rPl[i];
            *(uint4*)&gDst[dst]  = rG[i];
        }
    };

    // ---------------- prologue: theta (log2e-scaled), C-range split across halves
    const int half = wave >> 3;                 // 0: c0 in {0,64}; 1: {128,192}
    const int wci8 = (wave & 7) * 16;           // ci rows covered by this wave
    f32x4 th[4];
#pragma unroll
    for (int j = 0; j < 4; j++)
#pragma unroll
        for (int e = 0; e < 4; e++) th[j][e] = 0.f;

    for (int s = 0; s < 2; s++) {
        {   // each 512-thread half stages its own c0 chunk of x (transpose+split)
            int set = tid >> 9;                 // == wave>>3
            int t = tid & 511;
            int cp = t >> 4, n4 = (t & 15) * 4;
            int myc0 = set * 128 + s * 64;
            unsigned short* dXh = set ? sXhB : sXhA;
            unsigned short* dXl = set ? sXlB : sXlA;
            const float* xp = x + ((size_t)(b * NC + myc0 + 2 * cp)) * NN + n0 + n4;
            float4 a = *(const float4*)xp;
            float4 c = *(const float4*)(xp + NN);
            float av[4] = { a.x, a.y, a.z, a.w };
            float cv4[4] = { c.x, c.y, c.z, c.w };
#pragma unroll
            for (int j = 0; j < 4; j++) {
                unsigned short ha = f2bf(av[j]), hc = f2bf(cv4[j]);
                unsigned short la = f2bf(av[j] - bf2f(ha)), lc = f2bf(cv4[j] - bf2f(hc));
                *(unsigned int*)&dXh[(n4 + j) * 72 + 2 * cp] =
                    (unsigned int)ha | ((unsigned int)hc << 16);
                *(unsigned int*)&dXl[(n4 + j) * 72 + 2 * cp] =
                    (unsigned int)la | ((unsigned int)lc << 16);
            }
        }
        __syncthreads();
        {
            int c0 = half * 128 + s * 64;
            const unsigned short* mXh = half ? sXhB : sXhA;
            const unsigned short* mXl = half ? sXlB : sXlA;
#pragma unroll
            for (int ks = 0; ks < 2; ks++) {
                size_t w = (size_t)(wci8 + col) * NC + c0 + ks * 32 + quad * 8;
                short8 ah = *(const short8*)&WtH[w];
                short8 al = *(const short8*)&WtL[w];
#pragma unroll
                for (int j = 0; j < 4; j++) {
                    short8 bh = *(const short8*)&mXh[(j * 16 + col) * 72 + ks * 32 + quad * 8];
                    short8 bl = *(const short8*)&mXl[(j * 16 + col) * 72 + ks * 32 + quad * 8];
                    th[j] = __builtin_amdgcn_mfma_f32_16x16x32_bf16(ah, bh, th[j], 0, 0, 0);
                    th[j] = __builtin_amdgcn_mfma_f32_16x16x32_bf16(ah, bl, th[j], 0, 0, 0);
                    th[j] = __builtin_amdgcn_mfma_f32_16x16x32_bf16(al, bh, th[j], 0, 0, 0);
                }
            }
        }
        __syncthreads();
    }
    // merge halves: half 0 writes f32 partials; half 1 adds, biases, splits hi/lo
    if (half == 0) {
#pragma unroll
        for (int j = 0; j < 4; j++) {
            int q = j * 16 + col;
            int ci = (wci8 + quad * 4) ^ ((q & 7) << 2);
            *(f32x4*)&sThF[q * 128 + ci] = th[j];
        }
    }
    __syncthreads();
    if (half == 1) {
#pragma unroll
        for (int j = 0; j < 4; j++) {
            int q = j * 16 + col;
            int cif = (wci8 + quad * 4) ^ ((q & 7) << 2);
            f32x4 o = *(const f32x4*)&sThF[q * 128 + cif];
            unsigned short h[4], l[4];
#pragma unroll
            for (int e = 0; e < 4; e++) {
                float v = o[e] + th[j][e] + bt[wci8 + quad * 4 + e] * LOG2E;
                h[e] = f2bf(v);
                l[e] = f2bf(v - bf2f(h[e]));
            }
            int cisw = (wci8 + quad * 4) ^ ((q & 7) << 3);
            uint2 hv, lv;
            hv.x = (unsigned int)h[0] | ((unsigned int)h[1] << 16);
            hv.y = (unsigned int)h[2] | ((unsigned int)h[3] << 16);
            lv.x = (unsigned int)l[0] | ((unsigned int)l[1] << 16);
            lv.y = (unsigned int)l[2] | ((unsigned int)l[3] << 16);
            *(uint2*)&sThH[q * 128 + cisw] = hv;
            *(uint2*)&sThL[q * 128 + cisw] = lv;
        }
    }
    __syncthreads();
    // theta fragments: this wave's 32-query half (2 qtiles), both grades
    short8 qh[2][4], ql[2][4];
#pragma unroll
    for (int qt = 0; qt < 2; qt++) {
        int qrow = qg * 32 + qt * 16 + col;
        int qsw = (col & 7) << 3;
#pragma unroll
        for (int ks = 0; ks < 4; ks++) {
            int off = (ks * 32 + quad * 8) ^ qsw;
            qh[qt][ks] = *(const short8*)&sThH[qrow * 128 + off];
            ql[qt][ks] = *(const short8*)&sThL[qrow * 128 + off];
        }
    }
    // prestage window 0 + window 1
    LOADTW(0);
    __syncthreads();                 // all waves done reading sThH/sThL
    STORETW(sGbase);                 // window 0 -> phi, G slot 0
    LOADTW(128);                     // window 1 -> regs
    __syncthreads();                 // window 0 visible

    // ---------------- main loop: 32 windows x 128 keys, 2 barriers/window
    f32x4 oacc[2];
#pragma unroll
    for (int i = 0; i < 2; i++)
#pragma unroll
        for (int e = 0; e < 4; e++) oacc[i][e] = 0.f;
    float li[2][4];
#pragma unroll
    for (int i = 0; i < 2; i++)
#pragma unroll
        for (int r = 0; r < 4; r++) li[i][r] = 0.f;

    auto stepw = [&](int gRd, int gWr, int m_next, bool do_stage, bool do_load) {
        // QK(w): 32 queries (regs) x this wave's 16-key sixteenth
        f32x4 S[2];
#pragma unroll
        for (int qt = 0; qt < 2; qt++)
#pragma unroll
            for (int e = 0; e < 4; e++) S[qt][e] = 0.f;
        {
            int kcol = kh * 16 + col;
            int ksw = (col & 7) << 3;
#pragma unroll
            for (int ks = 0; ks < 4; ks++) {
                int off = (ks * 32 + quad * 8) ^ ksw;
                short8 ph = *(const short8*)&sPhiH[kcol * 128 + off];
                short8 pl = *(const short8*)&sPhiL[kcol * 128 + off];
                S[0] = __builtin_amdgcn_mfma_f32_16x16x32_bf16(qh[0][ks], ph, S[0], 0, 0, 0);
                S[0] = __builtin_amdgcn_mfma_f32_16x16x32_bf16(qh[0][ks], pl, S[0], 0, 0, 0);
                S[0] = __builtin_amdgcn_mfma_f32_16x16x32_bf16(ql[0][ks], ph, S[0], 0, 0, 0);
                S[1] = __builtin_amdgcn_mfma_f32_16x16x32_bf16(qh[1][ks], ph, S[1], 0, 0, 0);
                S[1] = __builtin_amdgcn_mfma_f32_16x16x32_bf16(qh[1][ks], pl, S[1], 0, 0, 0);
                S[1] = __builtin_amdgcn_mfma_f32_16x16x32_bf16(ql[1][ks], ph, S[1], 0, 0, 0);
            }
        }
        // softmax + P write (swizzled)
#pragma unroll
        for (int qt = 0; qt < 2; qt++)
#pragma unroll
            for (int r = 0; r < 4; r++) {
                float p = exp2f(S[qt][r]);
                li[qt][r] += p;
                int q = qg * 32 + qt * 16 + quad * 4 + r;
                sPall[q * 128 + ((kh * 16 + col) ^ ((q & 7) << 3))] = f2bf(p);
            }
        __syncthreads();             // barB: P(w) visible; phi(w) reads done
        // PV(w): 16q x 32c over the window's 128 keys
        {
            int qrow = qv * 16 + col;
            int psw = (col & 7) << 3;
            const unsigned short* gB = sGbase + gRd;
            int g0 = (cv * 32 + col) * 128;
            int g1 = (cv * 32 + 16 + col) * 128;
#pragma unroll
            for (int ks = 0; ks < 4; ks++) {
                int off = (ks * 32 + quad * 8) ^ psw;
                short8 pf  = *(const short8*)&sPall[qrow * 128 + off];
                short8 af0 = *(const short8*)&gB[g0 + off];
                short8 af1 = *(const short8*)&gB[g1 + off];
                oacc[0] = __builtin_amdgcn_mfma_f32_16x16x32_bf16(af0, pf, oacc[0], 0, 0, 0);
                oacc[1] = __builtin_amdgcn_mfma_f32_16x16x32_bf16(af1, pf, oacc[1], 0, 0, 0);
            }
        }
        if (do_stage) STORETW(sGbase + gWr);   // phi(w+1) + G slot (w+1)&1
        if (do_load) LOADTW(m_next);           // window w+2 -> regs
        __syncthreads();             // barA: stores visible; P(w)/G(w) reads done
    };

    for (int it = 0; it < 15; ++it) {
        stepw(0, 16384, (2 * it + 2) * 128, true, true);       // even w
        stepw(16384, 0, (2 * it + 3) * 128, true, true);       // odd w
    }
    stepw(0, 16384, 0, true, false);     // w=30: stage window 31, no load
    stepw(16384, 0, 0, false, false);    // w=31

    // ---------------- li: reduce over 16 cols, merge the 8 kh slices
#pragma unroll
    for (int qt = 0; qt < 2; qt++)
#pragma unroll
        for (int r = 0; r < 4; r++) {
            float rs = li[qt][r];
#pragma unroll
            for (int off = 1; off < 16; off <<= 1) rs += __shfl_xor(rs, off);
            li[qt][r] = rs;
        }
    if (col == 0) {
#pragma unroll
        for (int qt = 0; qt < 2; qt++)
#pragma unroll
            for (int r = 0; r < 4; r++)
                sLi[wave * 32 + qt * 16 + quad * 4 + r] = li[qt][r];
    }
    __syncthreads();
    float inv;
    {
        int qgf = qv >> 1, qtf = qv & 1;
        float s = 0.f;
#pragma unroll
        for (int k8 = 0; k8 < 8; k8++)
            s += sLi[(qgf * 8 + k8) * 32 + qtf * 16 + col];
        inv = 1.0f / s;
    }

    // O -> LDS (bf16, swizzled), overlays dead sPhiH
#pragma unroll
    for (int ct = 0; ct < 2; ct++) {
        int q = qv * 16 + col;
        int ci = cv * 32 + ct * 16 + quad * 4;
        int cisw = ci ^ ((q & 7) << 3);
        uint2 v;
        unsigned short p0 = f2bf(oacc[ct][0] * inv);
        unsigned short p1 = f2bf(oacc[ct][1] * inv);
        unsigned short p2 = f2bf(oacc[ct][2] * inv);
        unsigned short p3 = f2bf(oacc[ct][3] * inv);
        v.x = (unsigned int)p0 | ((unsigned int)p1 << 16);
        v.y = (unsigned int)p2 | ((unsigned int)p3 << 16);
        *(uint2*)&sO[q * 128 + cisw] = v;
    }
    __syncthreads();
    // out-proj: wave's 16-o tile + bias + residual; Wo A-frags straight from global
    f32x4 acc[4];
#pragma unroll
    for (int j = 0; j < 4; j++)
#pragma unroll
        for (int e = 0; e < 4; e++) acc[j][e] = 0.f;
#pragma unroll
    for (int ks = 0; ks < 4; ks++) {
        short8 af2 = *(const short8*)&WoH[(size_t)(wave * 16 + col) * NCI + ks * 32 + quad * 8];
#pragma unroll
        for (int j = 0; j < 4; j++) {
            int row = j * 16 + col;
            short8 bf = *(const short8*)&sO[row * 128 + ((ks * 32 + quad * 8) ^ ((row & 7) << 3))];
            acc[j] = __builtin_amdgcn_mfma_f32_16x16x32_bf16(af2, bf, acc[j], 0, 0, 0);
        }
    }
#pragma unroll
    for (int j = 0; j < 4; j++)
#pragma unroll
        for (int e = 0; e < 4; e++) {
            int o = wave * 16 + quad * 4 + e;
            size_t idx = ((size_t)(b * NC + o)) * NN + n0 + j * 16 + col;
            y[idx] = acc[j][e] + bo[o] + x[idx];
        }
}

// ---------------------------------------------------------------- launch
extern "C" void kernel_launch(void* const* d_in, const int* in_sizes, int n_in,
                              void* d_out, int out_size, void* d_ws, size_t ws_size,
                              hipStream_t stream) {
    float* y = (float*)d_out;

    bool sizes_ok = (n_in == 9) &&
        in_sizes[0] == NB * NC * NN && in_sizes[1] == NCI * NC && in_sizes[2] == NCI &&
        in_sizes[3] == NCI * NC && in_sizes[4] == NCI && in_sizes[5] == NCI * NC &&
        in_sizes[6] == NCI && in_sizes[7] == NC * NCI && in_sizes[8] == NC &&
        out_size == NB * NC * NN;
    if (!sizes_ok) {
        k_fill<<<(out_size + 255) / 256, 256, 0, stream>>>(y, 777.0f, out_size);
        return;
    }
    if (ws_size < (size_t)16 * 1024 * 1024) {
        k_fill<<<(out_size + 255) / 256, 256, 0, stream>>>(y, 555.0f, out_size);
        return;
    }

    const float* x  = (const float*)d_in[0];
    const float* tw = (const float*)d_in[1];
    const float* tb = (const float*)d_in[2];
    const float* pw = (const float*)d_in[3];
    const float* pb = (const float*)d_in[4];
    const float* gw = (const float*)d_in[5];
    const float* gb = (const float*)d_in[6];
    const float* ow = (const float*)d_in[7];
    const float* obias = (const float*)d_in[8];

    unsigned short* ws16 = (unsigned short*)d_ws;
    unsigned short* phiH = ws16;                 // [B][N][Ci] bf16 hi
    unsigned short* phiL = ws16 + 2097152;       // [B][N][Ci] bf16 lo
    unsigned short* g    = ws16 + 4194304;       // [B][Ci][N] bf16
    unsigned short* wbuf = ws16 + 6291456;       // WtH,WtL,WpH,WpL,WgH,WoH
    unsigned short* WtH = wbuf,           *WtL = wbuf + 32768;
    unsigned short* WpH = wbuf + 65536,   *WpL = wbuf + 98304;
    unsigned short* WgH = wbuf + 131072,  *WoH = wbuf + 163840;

    k_split<<<dim3(128, 4), 256, 0, stream>>>(tw, pw, gw, ow, wbuf);
    k_qkv2<<<dim3(128, NB), 256, 0, stream>>>(x, WpH, WpL, WgH, pb, gb, phiH, phiL, g);
    k_attn<<<dim3(256), 1024, 0, stream>>>(x, WtH, WtL, tb, phiH, phiL, g, WoH, obias, y);
}

// Round 12
// 477.144 us; speedup vs baseline: 1.0632x; 1.0632x over previous
//
#include <hip/hip_runtime.h>
#include <stdint.h>

#define NB 4
#define NC 256
#define NCI 128
#define NN 4096

typedef __attribute__((ext_vector_type(8))) short short8;
typedef __attribute__((ext_vector_type(4))) float f32x4;

__device__ __forceinline__ float bf2f(unsigned short u) {
    union { unsigned int i; float f; } v; v.i = ((unsigned int)u) << 16; return v.f;
}
__device__ __forceinline__ unsigned short f2bf(float f) {
    union { unsigned int i; float f; } v; v.f = f;
    unsigned int b = v.i;
    b += 0x7FFFu + ((b >> 16) & 1u);   // RNE
    return (unsigned short)(b >> 16);
}

// ---------------------------------------------------------------- sentinel fill
__global__ void k_fill(float* __restrict__ p, float v, int n) {
    int i = blockIdx.x * blockDim.x + threadIdx.x;
    if (i < n) p[i] = v;
}

// ---------------------------------------------------------------- K0: weight split/convert
__global__ __launch_bounds__(256) void k_split(
    const float* __restrict__ Wt, const float* __restrict__ Wp,
    const float* __restrict__ Wg, const float* __restrict__ Wo,
    unsigned short* __restrict__ wbuf) {
    const float LOG2E = 1.4426950408889634f;
    int m = blockIdx.y;
    int i = blockIdx.x * 256 + threadIdx.x;
    if (m == 0) {
        float v = Wt[i] * LOG2E;
        unsigned short h = f2bf(v);
        wbuf[i] = h;
        wbuf[32768 + i] = f2bf(v - bf2f(h));
    } else if (m == 1) {
        float v = Wp[i];
        unsigned short h = f2bf(v);
        wbuf[65536 + i] = h;
        wbuf[98304 + i] = f2bf(v - bf2f(h));
    } else if (m == 2) {
        wbuf[131072 + i] = f2bf(Wg[i]);
    } else {
        wbuf[163840 + i] = f2bf(Wo[i]);
    }
}

// ---------------------------------------------------------------- K1: phi (hi/lo) + g projections
__global__ __launch_bounds__(256, 2) void k_qkv2(
    const float* __restrict__ x,
    const unsigned short* __restrict__ WpH, const unsigned short* __restrict__ WpL,
    const unsigned short* __restrict__ WgH,
    const float* __restrict__ bp, const float* __restrict__ bg,
    unsigned short* __restrict__ phiH, unsigned short* __restrict__ phiL,
    unsigned short* __restrict__ gout) {
    __shared__ __align__(16) unsigned short sXh[32 * 72];
    __shared__ __align__(16) unsigned short sXl[32 * 72];
    const int b = blockIdx.y, n0 = blockIdx.x * 32;
    const int tid = threadIdx.x, lane = tid & 63, wave = tid >> 6;
    const int col = lane & 15, quad = lane >> 4;
    const int wm = wave * 32;

    f32x4 accP[2][2], accG[2][2];
#pragma unroll
    for (int i = 0; i < 2; i++)
#pragma unroll
        for (int j = 0; j < 2; j++)
#pragma unroll
            for (int e = 0; e < 4; e++) { accP[i][j][e] = 0.f; accG[i][j][e] = 0.f; }

    for (int c0 = 0; c0 < NC; c0 += 64) {
        __syncthreads();
        short8 ah[2][2], al[2][2], ag[2][2];
#pragma unroll
        for (int ks = 0; ks < 2; ks++)
#pragma unroll
            for (int i = 0; i < 2; i++) {
                size_t w = (size_t)(wm + i * 16 + col) * NC + c0 + ks * 32 + quad * 8;
                ah[ks][i] = *(const short8*)&WpH[w];
                al[ks][i] = *(const short8*)&WpL[w];
                ag[ks][i] = *(const short8*)&WgH[w];
            }
        {
            int cp = tid >> 3, n4 = (tid & 7) * 4;
            const float* xp = x + ((size_t)(b * NC + c0 + 2 * cp)) * NN + n0 + n4;
            float4 a = *(const float4*)xp;
            float4 c = *(const float4*)(xp + NN);
            float av[4] = { a.x, a.y, a.z, a.w };
            float cv[4] = { c.x, c.y, c.z, c.w };
#pragma unroll
            for (int j = 0; j < 4; j++) {
                unsigned short ha = f2bf(av[j]), hc = f2bf(cv[j]);
                unsigned short la = f2bf(av[j] - bf2f(ha)), lc = f2bf(cv[j] - bf2f(hc));
                *(unsigned int*)&sXh[(n4 + j) * 72 + 2 * cp] =
                    (unsigned int)ha | ((unsigned int)hc << 16);
                *(unsigned int*)&sXl[(n4 + j) * 72 + 2 * cp] =
                    (unsigned int)la | ((unsigned int)lc << 16);
            }
        }
        __syncthreads();
#pragma unroll
        for (int ks = 0; ks < 2; ks++)
#pragma unroll
            for (int j = 0; j < 2; j++) {
                short8 bh = *(const short8*)&sXh[(j * 16 + col) * 72 + ks * 32 + quad * 8];
                short8 bl = *(const short8*)&sXl[(j * 16 + col) * 72 + ks * 32 + quad * 8];
#pragma unroll
                for (int i = 0; i < 2; i++) {
                    accP[i][j] = __builtin_amdgcn_mfma_f32_16x16x32_bf16(ah[ks][i], bh, accP[i][j], 0, 0, 0);
                    accP[i][j] = __builtin_amdgcn_mfma_f32_16x16x32_bf16(ah[ks][i], bl, accP[i][j], 0, 0, 0);
                    accP[i][j] = __builtin_amdgcn_mfma_f32_16x16x32_bf16(al[ks][i], bh, accP[i][j], 0, 0, 0);
                    accG[i][j] = __builtin_amdgcn_mfma_f32_16x16x32_bf16(ag[ks][i], bh, accG[i][j], 0, 0, 0);
                }
            }
    }
#pragma unroll
    for (int i = 0; i < 2; i++) {
        int mrow = wm + i * 16 + quad * 4;
#pragma unroll
        for (int j = 0; j < 2; j++) {
            int n = n0 + j * 16 + col;
            unsigned short h[4], l[4];
#pragma unroll
            for (int e = 0; e < 4; e++) {
                float v = accP[i][j][e] + bp[mrow + e];
                h[e] = f2bf(v);
                l[e] = f2bf(v - bf2f(h[e]));
            }
            uint2 hv, lv;
            hv.x = (unsigned int)h[0] | ((unsigned int)h[1] << 16);
            hv.y = (unsigned int)h[2] | ((unsigned int)h[3] << 16);
            lv.x = (unsigned int)l[0] | ((unsigned int)l[1] << 16);
            lv.y = (unsigned int)l[2] | ((unsigned int)l[3] << 16);
            *(uint2*)&phiH[((size_t)(b * NN + n)) * NCI + mrow] = hv;
            *(uint2*)&phiL[((size_t)(b * NN + n)) * NCI + mrow] = lv;
#pragma unroll
            for (int r = 0; r < 4; r++)
                gout[((size_t)(b * NCI + mrow + r)) * NN + n] = f2bf(accG[i][j][r] + bg[mrow + r]);
        }
    }
}

// ---------------------------------------------------------------- K2: fused attention, 16 waves
// R11 structure with the scratch-spill fix: staging registers are SIX NAMED
// uint4 scalars (rPh0/rPh1/rPl0/rPl1/rG0/rG1), hand-unrolled — R11's uint4
// arrays inside lambdas went to scratch (rule #20), costing 1.6 GB/dispatch
// of spill traffic. Block: batch b, 64 queries, 256 blocks = 1/CU, 1024
// threads = 4 waves/SIMD. 128-KEY WINDOWS; QK waves = 2qg x 8kh (theta in
// regs, phi fragment shared by only 2 waves); PV waves = 4qv x 4cv.
// Pipeline per window (2 barriers):
//   QK(w) [phi single buf] ; softmax+Pwrite(w) [P single buf]
//   [barB] PV(w) [P(w), G slot w&1] ; STORETW(w+1) ; LOADTW(w+2) [barA]
__global__ __launch_bounds__(1024, 4) void k_attn(
    const float* __restrict__ x,
    const unsigned short* __restrict__ WtH, const unsigned short* __restrict__ WtL,
    const float* __restrict__ bt,
    const unsigned short* __restrict__ phiH, const unsigned short* __restrict__ phiL,
    const unsigned short* __restrict__ gmat,
    const unsigned short* __restrict__ WoH, const float* __restrict__ bo,
    float* __restrict__ y) {
    const float LOG2E = 1.4426950408889634f;
    __shared__ __align__(16) char smem[149504];
    // main-loop regions
    unsigned short* sPhiH  = (unsigned short*)(smem);            // [128 k][128 ci] swz
    unsigned short* sPhiL  = (unsigned short*)(smem + 32768);    // [128 k][128 ci] swz
    unsigned short* sGbase = (unsigned short*)(smem + 65536);    // 2 x [128 c][128 k] swz
    unsigned short* sPall  = (unsigned short*)(smem + 131072);   // [64 q][128 k] swz
    float* sLi             = (float*)(smem + 147456);            // [16 waves][32 q]
    // prologue overlays (all dead before first main-loop store)
    unsigned short* sThH  = (unsigned short*)(smem);             // [64 q][128] swz
    unsigned short* sThL  = (unsigned short*)(smem + 16384);
    unsigned short* sXhA  = (unsigned short*)(smem + 32768);     // [64 n][72] linear
    unsigned short* sXlA  = (unsigned short*)(smem + 41984);
    unsigned short* sXhB  = (unsigned short*)(smem + 51200);
    unsigned short* sXlB  = (unsigned short*)(smem + 60416);
    float* sThF           = (float*)(smem + 32768);              // [64 q][128] f32 swz (after sX dead)
    // epilogue overlay
    unsigned short* sO    = (unsigned short*)(smem);             // [64 q][128] swz

    const int id = blockIdx.x;
    const int xcd = id & 7, slot = id >> 3;                      // slot 0..31
    const int b = xcd >> 1;                                      // batch pinned to 2 XCDs
    const int n0 = (slot * 2 + (xcd & 1)) * 64;

    const int tid = threadIdx.x, lane = tid & 63, wave = tid >> 6;  // wave 0..15
    const int col = lane & 15, quad = lane >> 4;
    // QK roles: 2 query-halves x 8 key-sixteenths of the 128-key window
    const int qg = wave >> 3, kh = wave & 7;
    // PV roles: 4 query-sixteenths x 4 channel-32s
    const int qv = wave & 3, cv = wave >> 2;

    // staging geometry (static): rowA = tid>>4 in 0..63, rowB = rowA+64
    const int rowA = tid >> 4, segA = tid & 15;
    const int rowB = rowA + 64;
    const int dstA = rowA * 128 + ((segA * 8) ^ ((rowA & 7) << 3));
    const int dstB = rowB * 128 + ((segA * 8) ^ ((rowA & 7) << 3));  // rowB&7==rowA&7

    // staged-window registers: NAMED scalars (never arrays — scratch hazard)
    uint4 rPh0, rPh1, rPl0, rPl1, rG0, rG1;
    auto LOADTW = [&](int kbase) {
        size_t spA = ((size_t)(b * NN + kbase + rowA)) * NCI + segA * 8;
        rPh0 = *(const uint4*)&phiH[spA];
        rPl0 = *(const uint4*)&phiL[spA];
        rG0  = *(const uint4*)&gmat[((size_t)(b * NCI + rowA)) * NN + kbase + segA * 8];
        size_t spB = ((size_t)(b * NN + kbase + rowB)) * NCI + segA * 8;
        rPh1 = *(const uint4*)&phiH[spB];
        rPl1 = *(const uint4*)&phiL[spB];
        rG1  = *(const uint4*)&gmat[((size_t)(b * NCI + rowB)) * NN + kbase + segA * 8];
    };
    auto STORETW = [&](unsigned short* gDst) {
        *(uint4*)&sPhiH[dstA] = rPh0;
        *(uint4*)&sPhiL[dstA] = rPl0;
        *(uint4*)&gDst[dstA]  = rG0;
        *(uint4*)&sPhiH[dstB] = rPh1;
        *(uint4*)&sPhiL[dstB] = rPl1;
        *(uint4*)&gDst[dstB]  = rG1;
    };

    // ---------------- prologue: theta (log2e-scaled), C-range split across halves
    const int half = wave >> 3;                 // 0: c0 in {0,64}; 1: {128,192}
    const int wci8 = (wave & 7) * 16;           // ci rows covered by this wave
    f32x4 th[4];
#pragma unroll
    for (int j = 0; j < 4; j++)
#pragma unroll
        for (int e = 0; e < 4; e++) th[j][e] = 0.f;

    for (int s = 0; s < 2; s++) {
        {   // each 512-thread half stages its own c0 chunk of x (transpose+split)
            int set = tid >> 9;                 // == wave>>3
            int t = tid & 511;
            int cp = t >> 4, n4 = (t & 15) * 4;
            int myc0 = set * 128 + s * 64;
            unsigned short* dXh = set ? sXhB : sXhA;
            unsigned short* dXl = set ? sXlB : sXlA;
            const float* xp = x + ((size_t)(b * NC + myc0 + 2 * cp)) * NN + n0 + n4;
            float4 a = *(const float4*)xp;
            float4 c = *(const float4*)(xp + NN);
            float av[4] = { a.x, a.y, a.z, a.w };
            float cv4[4] = { c.x, c.y, c.z, c.w };
#pragma unroll
            for (int j = 0; j < 4; j++) {
                unsigned short ha = f2bf(av[j]), hc = f2bf(cv4[j]);
                unsigned short la = f2bf(av[j] - bf2f(ha)), lc = f2bf(cv4[j] - bf2f(hc));
                *(unsigned int*)&dXh[(n4 + j) * 72 + 2 * cp] =
                    (unsigned int)ha | ((unsigned int)hc << 16);
                *(unsigned int*)&dXl[(n4 + j) * 72 + 2 * cp] =
                    (unsigned int)la | ((unsigned int)lc << 16);
            }
        }
        __syncthreads();
        {
            int c0 = half * 128 + s * 64;
            const unsigned short* mXh = half ? sXhB : sXhA;
            const unsigned short* mXl = half ? sXlB : sXlA;
#pragma unroll
            for (int ks = 0; ks < 2; ks++) {
                size_t w = (size_t)(wci8 + col) * NC + c0 + ks * 32 + quad * 8;
                short8 ah = *(const short8*)&WtH[w];
                short8 al = *(const short8*)&WtL[w];
#pragma unroll
                for (int j = 0; j < 4; j++) {
                    short8 bh = *(const short8*)&mXh[(j * 16 + col) * 72 + ks * 32 + quad * 8];
                    short8 bl = *(const short8*)&mXl[(j * 16 + col) * 72 + ks * 32 + quad * 8];
                    th[j] = __builtin_amdgcn_mfma_f32_16x16x32_bf16(ah, bh, th[j], 0, 0, 0);
                    th[j] = __builtin_amdgcn_mfma_f32_16x16x32_bf16(ah, bl, th[j], 0, 0, 0);
                    th[j] = __builtin_amdgcn_mfma_f32_16x16x32_bf16(al, bh, th[j], 0, 0, 0);
                }
            }
        }
        __syncthreads();
    }
    // merge halves: half 0 writes f32 partials; half 1 adds, biases, splits hi/lo
    if (half == 0) {
#pragma unroll
        for (int j = 0; j < 4; j++) {
            int q = j * 16 + col;
            int ci = (wci8 + quad * 4) ^ ((q & 7) << 2);
            *(f32x4*)&sThF[q * 128 + ci] = th[j];
        }
    }
    __syncthreads();
    if (half == 1) {
#pragma unroll
        for (int j = 0; j < 4; j++) {
            int q = j * 16 + col;
            int cif = (wci8 + quad * 4) ^ ((q & 7) << 2);
            f32x4 o = *(const f32x4*)&sThF[q * 128 + cif];
            unsigned short h[4], l[4];
#pragma unroll
            for (int e = 0; e < 4; e++) {
                float v = o[e] + th[j][e] + bt[wci8 + quad * 4 + e] * LOG2E;
                h[e] = f2bf(v);
                l[e] = f2bf(v - bf2f(h[e]));
            }
            int cisw = (wci8 + quad * 4) ^ ((q & 7) << 3);
            uint2 hv, lv;
            hv.x = (unsigned int)h[0] | ((unsigned int)h[1] << 16);
            hv.y = (unsigned int)h[2] | ((unsigned int)h[3] << 16);
            lv.x = (unsigned int)l[0] | ((unsigned int)l[1] << 16);
            lv.y = (unsigned int)l[2] | ((unsigned int)l[3] << 16);
            *(uint2*)&sThH[q * 128 + cisw] = hv;
            *(uint2*)&sThL[q * 128 + cisw] = lv;
        }
    }
    __syncthreads();
    // theta fragments: this wave's 32-query half (2 qtiles), both grades
    short8 qh[2][4], ql[2][4];
#pragma unroll
    for (int qt = 0; qt < 2; qt++) {
        int qrow = qg * 32 + qt * 16 + col;
        int qsw = (col & 7) << 3;
#pragma unroll
        for (int ks = 0; ks < 4; ks++) {
            int off = (ks * 32 + quad * 8) ^ qsw;
            qh[qt][ks] = *(const short8*)&sThH[qrow * 128 + off];
            ql[qt][ks] = *(const short8*)&sThL[qrow * 128 + off];
        }
    }
    // prestage window 0 + window 1
    LOADTW(0);
    __syncthreads();                 // all waves done reading sThH/sThL
    STORETW(sGbase);                 // window 0 -> phi, G slot 0
    LOADTW(128);                     // window 1 -> regs
    __syncthreads();                 // window 0 visible

    // ---------------- main loop: 32 windows x 128 keys, 2 barriers/window
    f32x4 oacc[2];
#pragma unroll
    for (int i = 0; i < 2; i++)
#pragma unroll
        for (int e = 0; e < 4; e++) oacc[i][e] = 0.f;
    float li[2][4];
#pragma unroll
    for (int i = 0; i < 2; i++)
#pragma unroll
        for (int r = 0; r < 4; r++) li[i][r] = 0.f;

    auto stepw = [&](int gRd, int gWr, int m_next, bool do_stage, bool do_load) {
        // QK(w): 32 queries (regs) x this wave's 16-key sixteenth
        f32x4 S[2];
#pragma unroll
        for (int qt = 0; qt < 2; qt++)
#pragma unroll
            for (int e = 0; e < 4; e++) S[qt][e] = 0.f;
        {
            int kcol = kh * 16 + col;
            int ksw = (col & 7) << 3;
#pragma unroll
            for (int ks = 0; ks < 4; ks++) {
                int off = (ks * 32 + quad * 8) ^ ksw;
                short8 ph = *(const short8*)&sPhiH[kcol * 128 + off];
                short8 pl = *(const short8*)&sPhiL[kcol * 128 + off];
                S[0] = __builtin_amdgcn_mfma_f32_16x16x32_bf16(qh[0][ks], ph, S[0], 0, 0, 0);
                S[0] = __builtin_amdgcn_mfma_f32_16x16x32_bf16(qh[0][ks], pl, S[0], 0, 0, 0);
                S[0] = __builtin_amdgcn_mfma_f32_16x16x32_bf16(ql[0][ks], ph, S[0], 0, 0, 0);
                S[1] = __builtin_amdgcn_mfma_f32_16x16x32_bf16(qh[1][ks], ph, S[1], 0, 0, 0);
                S[1] = __builtin_amdgcn_mfma_f32_16x16x32_bf16(qh[1][ks], pl, S[1], 0, 0, 0);
                S[1] = __builtin_amdgcn_mfma_f32_16x16x32_bf16(ql[1][ks], ph, S[1], 0, 0, 0);
            }
        }
        // softmax + P write (swizzled)
#pragma unroll
        for (int qt = 0; qt < 2; qt++)
#pragma unroll
            for (int r = 0; r < 4; r++) {
                float p = exp2f(S[qt][r]);
                li[qt][r] += p;
                int q = qg * 32 + qt * 16 + quad * 4 + r;
                sPall[q * 128 + ((kh * 16 + col) ^ ((q & 7) << 3))] = f2bf(p);
            }
        __syncthreads();             // barB: P(w) visible; phi(w) reads done
        // PV(w): 16q x 32c over the window's 128 keys
        {
            int qrow = qv * 16 + col;
            int psw = (col & 7) << 3;
            const unsigned short* gB = sGbase + gRd;
            int g0 = (cv * 32 + col) * 128;
            int g1 = (cv * 32 + 16 + col) * 128;
#pragma unroll
            for (int ks = 0; ks < 4; ks++) {
                int off = (ks * 32 + quad * 8) ^ psw;
                short8 pf  = *(const short8*)&sPall[qrow * 128 + off];
                short8 af0 = *(const short8*)&gB[g0 + off];
                short8 af1 = *(const short8*)&gB[g1 + off];
                oacc[0] = __builtin_amdgcn_mfma_f32_16x16x32_bf16(af0, pf, oacc[0], 0, 0, 0);
                oacc[1] = __builtin_amdgcn_mfma_f32_16x16x32_bf16(af1, pf, oacc[1], 0, 0, 0);
            }
        }
        if (do_stage) STORETW(sGbase + gWr);   // phi(w+1) + G slot (w+1)&1
        if (do_load) LOADTW(m_next);           // window w+2 -> regs
        __syncthreads();             // barA: stores visible; P(w)/G(w) reads done
    };

    for (int it = 0; it < 15; ++it) {
        stepw(0, 16384, (2 * it + 2) * 128, true, true);       // even w
        stepw(16384, 0, (2 * it + 3) * 128, true, true);       // odd w
    }
    stepw(0, 16384, 0, true, false);     // w=30: stage window 31, no load
    stepw(16384, 0, 0, false, false);    // w=31

    // ---------------- li: reduce over 16 cols, merge the 8 kh slices
#pragma unroll
    for (int qt = 0; qt < 2; qt++)
#pragma unroll
        for (int r = 0; r < 4; r++) {
            float rs = li[qt][r];
#pragma unroll
            for (int off = 1; off < 16; off <<= 1) rs += __shfl_xor(rs, off);
            li[qt][r] = rs;
        }
    if (col == 0) {
#pragma unroll
        for (int qt = 0; qt < 2; qt++)
#pragma unroll
            for (int r = 0; r < 4; r++)
                sLi[wave * 32 + qt * 16 + quad * 4 + r] = li[qt][r];
    }
    __syncthreads();
    float inv;
    {
        int qgf = qv >> 1, qtf = qv & 1;
        float s = 0.f;
#pragma unroll
        for (int k8 = 0; k8 < 8; k8++)
            s += sLi[(qgf * 8 + k8) * 32 + qtf * 16 + col];
        inv = 1.0f / s;
    }

    // O -> LDS (bf16, swizzled), overlays dead sPhiH
#pragma unroll
    for (int ct = 0; ct < 2; ct++) {
        int q = qv * 16 + col;
        int ci = cv * 32 + ct * 16 + quad * 4;
        int cisw = ci ^ ((q & 7) << 3);
        uint2 v;
        unsigned short p0 = f2bf(oacc[ct][0] * inv);
        unsigned short p1 = f2bf(oacc[ct][1] * inv);
        unsigned short p2 = f2bf(oacc[ct][2] * inv);
        unsigned short p3 = f2bf(oacc[ct][3] * inv);
        v.x = (unsigned int)p0 | ((unsigned int)p1 << 16);
        v.y = (unsigned int)p2 | ((unsigned int)p3 << 16);
        *(uint2*)&sO[q * 128 + cisw] = v;
    }
    __syncthreads();
    // out-proj: wave's 16-o tile + bias + residual; Wo A-frags straight from global
    f32x4 acc[4];
#pragma unroll
    for (int j = 0; j < 4; j++)
#pragma unroll
        for (int e = 0; e < 4; e++) acc[j][e] = 0.f;
#pragma unroll
    for (int ks = 0; ks < 4; ks++) {
        short8 af2 = *(const short8*)&WoH[(size_t)(wave * 16 + col) * NCI + ks * 32 + quad * 8];
#pragma unroll
        for (int j = 0; j < 4; j++) {
            int row = j * 16 + col;
            short8 bf = *(const short8*)&sO[row * 128 + ((ks * 32 + quad * 8) ^ ((row & 7) << 3))];
            acc[j] = __builtin_amdgcn_mfma_f32_16x16x32_bf16(af2, bf, acc[j], 0, 0, 0);
        }
    }
#pragma unroll
    for (int j = 0; j < 4; j++)
#pragma unroll
        for (int e = 0; e < 4; e++) {
            int o = wave * 16 + quad * 4 + e;
            size_t idx = ((size_t)(b * NC + o)) * NN + n0 + j * 16 + col;
            y[idx] = acc[j][e] + bo[o] + x[idx];
        }
}

// ---------------------------------------------------------------- launch
extern "C" void kernel_launch(void* const* d_in, const int* in_sizes, int n_in,
                              void* d_out, int out_size, void* d_ws, size_t ws_size,
                              hipStream_t stream) {
    float* y = (float*)d_out;

    bool sizes_ok = (n_in == 9) &&
        in_sizes[0] == NB * NC * NN && in_sizes[1] == NCI * NC && in_sizes[2] == NCI &&
        in_sizes[3] == NCI * NC && in_sizes[4] == NCI && in_sizes[5] == NCI * NC &&
        in_sizes[6] == NCI && in_sizes[7] == NC * NCI && in_sizes[8] == NC &&
        out_size == NB * NC * NN;
    if (!sizes_ok) {
        k_fill<<<(out_size + 255) / 256, 256, 0, stream>>>(y, 777.0f, out_size);
        return;
    }
    if (ws_size < (size_t)16 * 1024 * 1024) {
        k_fill<<<(out_size + 255) / 256, 256, 0, stream>>>(y, 555.0f, out_size);
        return;
    }

    const float* x  = (const float*)d_in[0];
    const float* tw = (const float*)d_in[1];
    const float* tb = (const float*)d_in[2];
    const float* pw = (const float*)d_in[3];
    const float* pb = (const float*)d_in[4];
    const float* gw = (const float*)d_in[5];
    const float* gb = (const float*)d_in[6];
    const float* ow = (const float*)d_in[7];
    const float* obias = (const float*)d_in[8];

    unsigned short* ws16 = (unsigned short*)d_ws;
    unsigned short* phiH = ws16;                 // [B][N][Ci] bf16 hi
    unsigned short* phiL = ws16 + 2097152;       // [B][N][Ci] bf16 lo
    unsigned short* g    = ws16 + 4194304;       // [B][Ci][N] bf16
    unsigned short* wbuf = ws16 + 6291456;       // WtH,WtL,WpH,WpL,WgH,WoH
    unsigned short* WtH = wbuf,           *WtL = wbuf + 32768;
    unsigned short* WpH = wbuf + 65536,   *WpL = wbuf + 98304;
    unsigned short* WgH = wbuf + 131072,  *WoH = wbuf + 163840;

    k_split<<<dim3(128, 4), 256, 0, stream>>>(tw, pw, gw, ow, wbuf);
    k_qkv2<<<dim3(128, NB), 256, 0, stream>>>(x, WpH, WpL, WgH, pb, gb, phiH, phiL, g);
    k_attn<<<dim3(256), 1024, 0, stream>>>(x, WtH, WtL, tb, phiH, phiL, g, WoH, obias, y);
}

// Round 13
// 319.520 us; speedup vs baseline: 1.5877x; 1.4933x over previous
//
#include <hip/hip_runtime.h>
#include <stdint.h>

#define NB 4
#define NC 256
#define NCI 128
#define NN 4096

typedef __attribute__((ext_vector_type(8))) short short8;
typedef __attribute__((ext_vector_type(4))) float f32x4;

#define GLOAD16(gp, lp) __builtin_amdgcn_global_load_lds( \
    (const __attribute__((address_space(1))) unsigned int*)(gp), \
    (__attribute__((address_space(3))) unsigned int*)(lp), 16, 0, 0)

__device__ __forceinline__ float bf2f(unsigned short u) {
    union { unsigned int i; float f; } v; v.i = ((unsigned int)u) << 16; return v.f;
}
__device__ __forceinline__ unsigned short f2bf(float f) {
    union { unsigned int i; float f; } v; v.f = f;
    unsigned int b = v.i;
    b += 0x7FFFu + ((b >> 16) & 1u);   // RNE
    return (unsigned short)(b >> 16);
}

// ---------------------------------------------------------------- sentinel fill
__global__ void k_fill(float* __restrict__ p, float v, int n) {
    int i = blockIdx.x * blockDim.x + threadIdx.x;
    if (i < n) p[i] = v;
}

// ---------------------------------------------------------------- K0: weight split/convert
__global__ __launch_bounds__(256) void k_split(
    const float* __restrict__ Wt, const float* __restrict__ Wp,
    const float* __restrict__ Wg, const float* __restrict__ Wo,
    unsigned short* __restrict__ wbuf) {
    const float LOG2E = 1.4426950408889634f;
    int m = blockIdx.y;
    int i = blockIdx.x * 256 + threadIdx.x;
    if (m == 0) {
        float v = Wt[i] * LOG2E;
        unsigned short h = f2bf(v);
        wbuf[i] = h;
        wbuf[32768 + i] = f2bf(v - bf2f(h));
    } else if (m == 1) {
        float v = Wp[i];
        unsigned short h = f2bf(v);
        wbuf[65536 + i] = h;
        wbuf[98304 + i] = f2bf(v - bf2f(h));
    } else if (m == 2) {
        wbuf[131072 + i] = f2bf(Wg[i]);
    } else {
        wbuf[163840 + i] = f2bf(Wo[i]);
    }
}

// ---------------------------------------------------------------- K1: phi (hi/lo) + g projections
__global__ __launch_bounds__(256, 2) void k_qkv2(
    const float* __restrict__ x,
    const unsigned short* __restrict__ WpH, const unsigned short* __restrict__ WpL,
    const unsigned short* __restrict__ WgH,
    const float* __restrict__ bp, const float* __restrict__ bg,
    unsigned short* __restrict__ phiH, unsigned short* __restrict__ phiL,
    unsigned short* __restrict__ gout) {
    __shared__ __align__(16) unsigned short sXh[32 * 72];
    __shared__ __align__(16) unsigned short sXl[32 * 72];
    const int b = blockIdx.y, n0 = blockIdx.x * 32;
    const int tid = threadIdx.x, lane = tid & 63, wave = tid >> 6;
    const int col = lane & 15, quad = lane >> 4;
    const int wm = wave * 32;

    f32x4 accP[2][2], accG[2][2];
#pragma unroll
    for (int i = 0; i < 2; i++)
#pragma unroll
        for (int j = 0; j < 2; j++)
#pragma unroll
            for (int e = 0; e < 4; e++) { accP[i][j][e] = 0.f; accG[i][j][e] = 0.f; }

    for (int c0 = 0; c0 < NC; c0 += 64) {
        __syncthreads();
        short8 ah[2][2], al[2][2], ag[2][2];
#pragma unroll
        for (int ks = 0; ks < 2; ks++)
#pragma unroll
            for (int i = 0; i < 2; i++) {
                size_t w = (size_t)(wm + i * 16 + col) * NC + c0 + ks * 32 + quad * 8;
                ah[ks][i] = *(const short8*)&WpH[w];
                al[ks][i] = *(const short8*)&WpL[w];
                ag[ks][i] = *(const short8*)&WgH[w];
            }
        {
            int cp = tid >> 3, n4 = (tid & 7) * 4;
            const float* xp = x + ((size_t)(b * NC + c0 + 2 * cp)) * NN + n0 + n4;
            float4 a = *(const float4*)xp;
            float4 c = *(const float4*)(xp + NN);
            float av[4] = { a.x, a.y, a.z, a.w };
            float cv[4] = { c.x, c.y, c.z, c.w };
#pragma unroll
            for (int j = 0; j < 4; j++) {
                unsigned short ha = f2bf(av[j]), hc = f2bf(cv[j]);
                unsigned short la = f2bf(av[j] - bf2f(ha)), lc = f2bf(cv[j] - bf2f(hc));
                *(unsigned int*)&sXh[(n4 + j) * 72 + 2 * cp] =
                    (unsigned int)ha | ((unsigned int)hc << 16);
                *(unsigned int*)&sXl[(n4 + j) * 72 + 2 * cp] =
                    (unsigned int)la | ((unsigned int)lc << 16);
            }
        }
        __syncthreads();
#pragma unroll
        for (int ks = 0; ks < 2; ks++)
#pragma unroll
            for (int j = 0; j < 2; j++) {
                short8 bh = *(const short8*)&sXh[(j * 16 + col) * 72 + ks * 32 + quad * 8];
                short8 bl = *(const short8*)&sXl[(j * 16 + col) * 72 + ks * 32 + quad * 8];
#pragma unroll
                for (int i = 0; i < 2; i++) {
                    accP[i][j] = __builtin_amdgcn_mfma_f32_16x16x32_bf16(ah[ks][i], bh, accP[i][j], 0, 0, 0);
                    accP[i][j] = __builtin_amdgcn_mfma_f32_16x16x32_bf16(ah[ks][i], bl, accP[i][j], 0, 0, 0);
                    accP[i][j] = __builtin_amdgcn_mfma_f32_16x16x32_bf16(al[ks][i], bh, accP[i][j], 0, 0, 0);
                    accG[i][j] = __builtin_amdgcn_mfma_f32_16x16x32_bf16(ag[ks][i], bh, accG[i][j], 0, 0, 0);
                }
            }
    }
#pragma unroll
    for (int i = 0; i < 2; i++) {
        int mrow = wm + i * 16 + quad * 4;
#pragma unroll
        for (int j = 0; j < 2; j++) {
            int n = n0 + j * 16 + col;
            unsigned short h[4], l[4];
#pragma unroll
            for (int e = 0; e < 4; e++) {
                float v = accP[i][j][e] + bp[mrow + e];
                h[e] = f2bf(v);
                l[e] = f2bf(v - bf2f(h[e]));
            }
            uint2 hv, lv;
            hv.x = (unsigned int)h[0] | ((unsigned int)h[1] << 16);
            hv.y = (unsigned int)h[2] | ((unsigned int)h[3] << 16);
            lv.x = (unsigned int)l[0] | ((unsigned int)l[1] << 16);
            lv.y = (unsigned int)l[2] | ((unsigned int)l[3] << 16);
            *(uint2*)&phiH[((size_t)(b * NN + n)) * NCI + mrow] = hv;
            *(uint2*)&phiL[((size_t)(b * NN + n)) * NCI + mrow] = lv;
#pragma unroll
            for (int r = 0; r < 4; r++)
                gout[((size_t)(b * NCI + mrow + r)) * NN + n] = f2bf(accG[i][j][r] + bg[mrow + r]);
        }
    }
}

// ---------------------------------------------------------------- K2: fused attention, 16 waves
// R12 structure with staging via global_load_lds (width=16) — removes the 24
// staged VGPRs whose spill caused R11/R12's 1.5 GB/dispatch scratch traffic
// (theta qh/ql[2][4]=64 VGPR + staging 24 + acc blew the 128/wave cap a
// 16-wave block imposes). LDS dest is LINEAR (gload_lds can't scatter, m104);
// the XOR swizzle moves to the per-lane GLOBAL source (srcseg = seg^(row&7),
// rule #21) so read-side swizzle is unchanged. Pipeline per 128-key window:
//   QK(w) [phi 1-buf] ; softmax+Pwrite(w) [P 1-buf]
//   [barB] issue 6 gload_lds for (w+1) ; PV(w) [P(w), G slot w&1] hides L2 lat
//   [barA] (syncthreads vmcnt-drain lands the writes)
// Hazards: phi writes issued post-barB (all QK(w) reads drained block-wide);
// G write slot (w+1)&1 != read slot w&1; P written pre-barB, read pre-barA.
__global__ __launch_bounds__(1024, 4) void k_attn(
    const float* __restrict__ x,
    const unsigned short* __restrict__ WtH, const unsigned short* __restrict__ WtL,
    const float* __restrict__ bt,
    const unsigned short* __restrict__ phiH, const unsigned short* __restrict__ phiL,
    const unsigned short* __restrict__ gmat,
    const unsigned short* __restrict__ WoH, const float* __restrict__ bo,
    float* __restrict__ y) {
    const float LOG2E = 1.4426950408889634f;
    __shared__ __align__(16) char smem[149504];
    // main-loop regions
    unsigned short* sPhiH  = (unsigned short*)(smem);            // [128 k][128 ci] swz
    unsigned short* sPhiL  = (unsigned short*)(smem + 32768);    // [128 k][128 ci] swz
    unsigned short* sGbase = (unsigned short*)(smem + 65536);    // 2 x [128 c][128 k] swz
    unsigned short* sPall  = (unsigned short*)(smem + 131072);   // [64 q][128 k] swz
    float* sLi             = (float*)(smem + 147456);            // [16 waves][32 q]
    // prologue overlays (all dead before first main-loop store)
    unsigned short* sThH  = (unsigned short*)(smem);             // [64 q][128] swz
    unsigned short* sThL  = (unsigned short*)(smem + 16384);
    unsigned short* sXhA  = (unsigned short*)(smem + 32768);     // [64 n][72] linear
    unsigned short* sXlA  = (unsigned short*)(smem + 41984);
    unsigned short* sXhB  = (unsigned short*)(smem + 51200);
    unsigned short* sXlB  = (unsigned short*)(smem + 60416);
    float* sThF           = (float*)(smem + 32768);              // [64 q][128] f32 swz (after sX dead)
    // epilogue overlay
    unsigned short* sO    = (unsigned short*)(smem);             // [64 q][128] swz

    const int id = blockIdx.x;
    const int xcd = id & 7, slot = id >> 3;                      // slot 0..31
    const int b = xcd >> 1;                                      // batch pinned to 2 XCDs
    const int n0 = (slot * 2 + (xcd & 1)) * 64;

    const int tid = threadIdx.x, lane = tid & 63, wave = tid >> 6;  // wave 0..15
    const int col = lane & 15, quad = lane >> 4;
    // QK roles: 2 query-halves x 8 key-sixteenths of the 128-key window
    const int qg = wave >> 3, kh = wave & 7;
    // PV roles: 4 query-sixteenths x 4 channel-32s
    const int qv = wave & 3, cv = wave >> 2;

    // staging geometry: wave w lane l covers j=w*64+l (call A) and j+1024 (call B)
    // row = j>>4, seg = j&15; LDS linear dst = j*16B; global src seg = seg^(row&7)
    const int prow = wave * 4 + (lane >> 4);        // 0..63 (call A); +64 call B
    const int psrc = (lane & 15) ^ (prow & 7);
    const int ldsA = wave * 512;                    // shorts
    const int ldsB = 8192 + wave * 512;

    auto ISSUE = [&](int kbase, int gslot) {
        const unsigned short* gPh = phiH + ((size_t)(b * NN + kbase + prow)) * NCI + psrc * 8;
        const unsigned short* gPl = phiL + ((size_t)(b * NN + kbase + prow)) * NCI + psrc * 8;
        const unsigned short* gG  = gmat + ((size_t)(b * NCI + prow)) * NN + kbase + psrc * 8;
        GLOAD16(gPh, &sPhiH[ldsA]);
        GLOAD16(gPl, &sPhiL[ldsA]);
        GLOAD16(gG,  &sGbase[gslot + ldsA]);
        GLOAD16(gPh + (size_t)64 * NCI, &sPhiH[ldsB]);
        GLOAD16(gPl + (size_t)64 * NCI, &sPhiL[ldsB]);
        GLOAD16(gG + (size_t)64 * NN,   &sGbase[gslot + ldsB]);
    };

    // ---------------- prologue: theta (log2e-scaled), C-range split across halves
    const int half = wave >> 3;                 // 0: c0 in {0,64}; 1: {128,192}
    const int wci8 = (wave & 7) * 16;           // ci rows covered by this wave
    f32x4 th[4];
#pragma unroll
    for (int j = 0; j < 4; j++)
#pragma unroll
        for (int e = 0; e < 4; e++) th[j][e] = 0.f;

    for (int s = 0; s < 2; s++) {
        {   // each 512-thread half stages its own c0 chunk of x (transpose+split)
            int set = tid >> 9;                 // == wave>>3
            int t = tid & 511;
            int cp = t >> 4, n4 = (t & 15) * 4;
            int myc0 = set * 128 + s * 64;
            unsigned short* dXh = set ? sXhB : sXhA;
            unsigned short* dXl = set ? sXlB : sXlA;
            const float* xp = x + ((size_t)(b * NC + myc0 + 2 * cp)) * NN + n0 + n4;
            float4 a = *(const float4*)xp;
            float4 c = *(const float4*)(xp + NN);
            float av[4] = { a.x, a.y, a.z, a.w };
            float cv4[4] = { c.x, c.y, c.z, c.w };
#pragma unroll
            for (int j = 0; j < 4; j++) {
                unsigned short ha = f2bf(av[j]), hc = f2bf(cv4[j]);
                unsigned short la = f2bf(av[j] - bf2f(ha)), lc = f2bf(cv4[j] - bf2f(hc));
                *(unsigned int*)&dXh[(n4 + j) * 72 + 2 * cp] =
                    (unsigned int)ha | ((unsigned int)hc << 16);
                *(unsigned int*)&dXl[(n4 + j) * 72 + 2 * cp] =
                    (unsigned int)la | ((unsigned int)lc << 16);
            }
        }
        __syncthreads();
        {
            int c0 = half * 128 + s * 64;
            const unsigned short* mXh = half ? sXhB : sXhA;
            const unsigned short* mXl = half ? sXlB : sXlA;
#pragma unroll
            for (int ks = 0; ks < 2; ks++) {
                size_t w = (size_t)(wci8 + col) * NC + c0 + ks * 32 + quad * 8;
                short8 ah = *(const short8*)&WtH[w];
                short8 al = *(const short8*)&WtL[w];
#pragma unroll
                for (int j = 0; j < 4; j++) {
                    short8 bh = *(const short8*)&mXh[(j * 16 + col) * 72 + ks * 32 + quad * 8];
                    short8 bl = *(const short8*)&mXl[(j * 16 + col) * 72 + ks * 32 + quad * 8];
                    th[j] = __builtin_amdgcn_mfma_f32_16x16x32_bf16(ah, bh, th[j], 0, 0, 0);
                    th[j] = __builtin_amdgcn_mfma_f32_16x16x32_bf16(ah, bl, th[j], 0, 0, 0);
                    th[j] = __builtin_amdgcn_mfma_f32_16x16x32_bf16(al, bh, th[j], 0, 0, 0);
                }
            }
        }
        __syncthreads();
    }
    // merge halves: half 0 writes f32 partials; half 1 adds, biases, splits hi/lo
    if (half == 0) {
#pragma unroll
        for (int j = 0; j < 4; j++) {
            int q = j * 16 + col;
            int ci = (wci8 + quad * 4) ^ ((q & 7) << 2);
            *(f32x4*)&sThF[q * 128 + ci] = th[j];
        }
    }
    __syncthreads();
    if (half == 1) {
#pragma unroll
        for (int j = 0; j < 4; j++) {
            int q = j * 16 + col;
            int cif = (wci8 + quad * 4) ^ ((q & 7) << 2);
            f32x4 o = *(const f32x4*)&sThF[q * 128 + cif];
            unsigned short h[4], l[4];
#pragma unroll
            for (int e = 0; e < 4; e++) {
                float v = o[e] + th[j][e] + bt[wci8 + quad * 4 + e] * LOG2E;
                h[e] = f2bf(v);
                l[e] = f2bf(v - bf2f(h[e]));
            }
            int cisw = (wci8 + quad * 4) ^ ((q & 7) << 3);
            uint2 hv, lv;
            hv.x = (unsigned int)h[0] | ((unsigned int)h[1] << 16);
            hv.y = (unsigned int)h[2] | ((unsigned int)h[3] << 16);
            lv.x = (unsigned int)l[0] | ((unsigned int)l[1] << 16);
            lv.y = (unsigned int)l[2] | ((unsigned int)l[3] << 16);
            *(uint2*)&sThH[q * 128 + cisw] = hv;
            *(uint2*)&sThL[q * 128 + cisw] = lv;
        }
    }
    __syncthreads();
    // theta fragments: this wave's 32-query half (2 qtiles), both grades
    short8 qh[2][4], ql[2][4];
#pragma unroll
    for (int qt = 0; qt < 2; qt++) {
        int qrow = qg * 32 + qt * 16 + col;
        int qsw = (col & 7) << 3;
#pragma unroll
        for (int ks = 0; ks < 4; ks++) {
            int off = (ks * 32 + quad * 8) ^ qsw;
            qh[qt][ks] = *(const short8*)&sThH[qrow * 128 + off];
            ql[qt][ks] = *(const short8*)&sThL[qrow * 128 + off];
        }
    }
    __syncthreads();                 // all waves done reading sThH/sThL
    ISSUE(0, 0);                     // window 0 -> phi, G slot 0 (direct to LDS)
    __syncthreads();                 // vmcnt drained: window 0 visible

    // ---------------- main loop: 32 windows x 128 keys, 2 barriers/window
    f32x4 oacc[2];
#pragma unroll
    for (int i = 0; i < 2; i++)
#pragma unroll
        for (int e = 0; e < 4; e++) oacc[i][e] = 0.f;
    float li[2][4];
#pragma unroll
    for (int i = 0; i < 2; i++)
#pragma unroll
        for (int r = 0; r < 4; r++) li[i][r] = 0.f;

    auto stepw = [&](int gRd, int gWr, int k_next, bool do_issue) {
        // QK(w): 32 queries (regs) x this wave's 16-key sixteenth
        f32x4 S[2];
#pragma unroll
        for (int qt = 0; qt < 2; qt++)
#pragma unroll
            for (int e = 0; e < 4; e++) S[qt][e] = 0.f;
        {
            int kcol = kh * 16 + col;
            int ksw = (col & 7) << 3;
#pragma unroll
            for (int ks = 0; ks < 4; ks++) {
                int off = (ks * 32 + quad * 8) ^ ksw;
                short8 ph = *(const short8*)&sPhiH[kcol * 128 + off];
                short8 pl = *(const short8*)&sPhiL[kcol * 128 + off];
                S[0] = __builtin_amdgcn_mfma_f32_16x16x32_bf16(qh[0][ks], ph, S[0], 0, 0, 0);
                S[0] = __builtin_amdgcn_mfma_f32_16x16x32_bf16(qh[0][ks], pl, S[0], 0, 0, 0);
                S[0] = __builtin_amdgcn_mfma_f32_16x16x32_bf16(ql[0][ks], ph, S[0], 0, 0, 0);
                S[1] = __builtin_amdgcn_mfma_f32_16x16x32_bf16(qh[1][ks], ph, S[1], 0, 0, 0);
                S[1] = __builtin_amdgcn_mfma_f32_16x16x32_bf16(qh[1][ks], pl, S[1], 0, 0, 0);
                S[1] = __builtin_amdgcn_mfma_f32_16x16x32_bf16(ql[1][ks], ph, S[1], 0, 0, 0);
            }
        }
        // softmax + P write (swizzled)
#pragma unroll
        for (int qt = 0; qt < 2; qt++)
#pragma unroll
            for (int r = 0; r < 4; r++) {
                float p = exp2f(S[qt][r]);
                li[qt][r] += p;
                int q = qg * 32 + qt * 16 + quad * 4 + r;
                sPall[q * 128 + ((kh * 16 + col) ^ ((q & 7) << 3))] = f2bf(p);
            }
        __syncthreads();             // barB: P(w) visible; phi(w) reads done block-wide
        // issue next window's staging (writes land before barA's vmcnt drain)
        if (do_issue) ISSUE(k_next, gWr);
        // PV(w): 16q x 32c over the window's 128 keys — hides staging latency
        {
            int qrow = qv * 16 + col;
            int psw = (col & 7) << 3;
            const unsigned short* gB = sGbase + gRd;
            int g0 = (cv * 32 + col) * 128;
            int g1 = (cv * 32 + 16 + col) * 128;
#pragma unroll
            for (int ks = 0; ks < 4; ks++) {
                int off = (ks * 32 + quad * 8) ^ psw;
                short8 pf  = *(const short8*)&sPall[qrow * 128 + off];
                short8 af0 = *(const short8*)&gB[g0 + off];
                short8 af1 = *(const short8*)&gB[g1 + off];
                oacc[0] = __builtin_amdgcn_mfma_f32_16x16x32_bf16(af0, pf, oacc[0], 0, 0, 0);
                oacc[1] = __builtin_amdgcn_mfma_f32_16x16x32_bf16(af1, pf, oacc[1], 0, 0, 0);
            }
        }
        __syncthreads();             // barA: staging landed; P(w)/G(w) reads done
    };

    for (int it = 0; it < 16; ++it) {
        stepw(0, 16384, (2 * it + 1) * 128, true);             // even w = 2it
        stepw(16384, 0, (2 * it + 2) * 128, it != 15);         // odd w = 2it+1
    }

    // ---------------- li: reduce over 16 cols, merge the 8 kh slices
#pragma unroll
    for (int qt = 0; qt < 2; qt++)
#pragma unroll
        for (int r = 0; r < 4; r++) {
            float rs = li[qt][r];
#pragma unroll
            for (int off = 1; off < 16; off <<= 1) rs += __shfl_xor(rs, off);
            li[qt][r] = rs;
        }
    if (col == 0) {
#pragma unroll
        for (int qt = 0; qt < 2; qt++)
#pragma unroll
            for (int r = 0; r < 4; r++)
                sLi[wave * 32 + qt * 16 + quad * 4 + r] = li[qt][r];
    }
    __syncthreads();
    float inv;
    {
        int qgf = qv >> 1, qtf = qv & 1;
        float s = 0.f;
#pragma unroll
        for (int k8 = 0; k8 < 8; k8++)
            s += sLi[(qgf * 8 + k8) * 32 + qtf * 16 + col];
        inv = 1.0f / s;
    }

    // O -> LDS (bf16, swizzled), overlays dead sPhiH
#pragma unroll
    for (int ct = 0; ct < 2; ct++) {
        int q = qv * 16 + col;
        int ci = cv * 32 + ct * 16 + quad * 4;
        int cisw = ci ^ ((q & 7) << 3);
        uint2 v;
        unsigned short p0 = f2bf(oacc[ct][0] * inv);
        unsigned short p1 = f2bf(oacc[ct][1] * inv);
        unsigned short p2 = f2bf(oacc[ct][2] * inv);
        unsigned short p3 = f2bf(oacc[ct][3] * inv);
        v.x = (unsigned int)p0 | ((unsigned int)p1 << 16);
        v.y = (unsigned int)p2 | ((unsigned int)p3 << 16);
        *(uint2*)&sO[q * 128 + cisw] = v;
    }
    __syncthreads();
    // out-proj: wave's 16-o tile + bias + residual; Wo A-frags straight from global
    f32x4 acc[4];
#pragma unroll
    for (int j = 0; j < 4; j++)
#pragma unroll
        for (int e = 0; e < 4; e++) acc[j][e] = 0.f;
#pragma unroll
    for (int ks = 0; ks < 4; ks++) {
        short8 af2 = *(const short8*)&WoH[(size_t)(wave * 16 + col) * NCI + ks * 32 + quad * 8];
#pragma unroll
        for (int j = 0; j < 4; j++) {
            int row = j * 16 + col;
            short8 bf = *(const short8*)&sO[row * 128 + ((ks * 32 + quad * 8) ^ ((row & 7) << 3))];
            acc[j] = __builtin_amdgcn_mfma_f32_16x16x32_bf16(af2, bf, acc[j], 0, 0, 0);
        }
    }
#pragma unroll
    for (int j = 0; j < 4; j++)
#pragma unroll
        for (int e = 0; e < 4; e++) {
            int o = wave * 16 + quad * 4 + e;
            size_t idx = ((size_t)(b * NC + o)) * NN + n0 + j * 16 + col;
            y[idx] = acc[j][e] + bo[o] + x[idx];
        }
}

// ---------------------------------------------------------------- launch
extern "C" void kernel_launch(void* const* d_in, const int* in_sizes, int n_in,
                              void* d_out, int out_size, void* d_ws, size_t ws_size,
                              hipStream_t stream) {
    float* y = (float*)d_out;

    bool sizes_ok = (n_in == 9) &&
        in_sizes[0] == NB * NC * NN && in_sizes[1] == NCI * NC && in_sizes[2] == NCI &&
        in_sizes[3] == NCI * NC && in_sizes[4] == NCI && in_sizes[5] == NCI * NC &&
        in_sizes[6] == NCI && in_sizes[7] == NC * NCI && in_sizes[8] == NC &&
        out_size == NB * NC * NN;
    if (!sizes_ok) {
        k_fill<<<(out_size + 255) / 256, 256, 0, stream>>>(y, 777.0f, out_size);
        return;
    }
    if (ws_size < (size_t)16 * 1024 * 1024) {
        k_fill<<<(out_size + 255) / 256, 256, 0, stream>>>(y, 555.0f, out_size);
        return;
    }

    const float* x  = (const float*)d_in[0];
    const float* tw = (const float*)d_in[1];
    const float* tb = (const float*)d_in[2];
    const float* pw = (const float*)d_in[3];
    const float* pb = (const float*)d_in[4];
    const float* gw = (const float*)d_in[5];
    const float* gb = (const float*)d_in[6];
    const float* ow = (const float*)d_in[7];
    const float* obias = (const float*)d_in[8];

    unsigned short* ws16 = (unsigned short*)d_ws;
    unsigned short* phiH = ws16;                 // [B][N][Ci] bf16 hi
    unsigned short* phiL = ws16 + 2097152;       // [B][N][Ci] bf16 lo
    unsigned short* g    = ws16 + 4194304;       // [B][Ci][N] bf16
    unsigned short* wbuf = ws16 + 6291456;       // WtH,WtL,WpH,WpL,WgH,WoH
    unsigned short* WtH = wbuf,           *WtL = wbuf + 32768;
    unsigned short* WpH = wbuf + 65536,   *WpL = wbuf + 98304;
    unsigned short* WgH = wbuf + 131072,  *WoH = wbuf + 163840;

    k_split<<<dim3(128, 4), 256, 0, stream>>>(tw, pw, gw, ow, wbuf);
    k_qkv2<<<dim3(128, NB), 256, 0, stream>>>(x, WpH, WpL, WgH, pb, gb, phiH, phiL, g);
    k_attn<<<dim3(256), 1024, 0, stream>>>(x, WtH, WtL, tb, phiH, phiL, g, WoH, obias, y);
}

// Round 14
// 192.976 us; speedup vs baseline: 2.6289x; 1.6558x over previous
//
#include <hip/hip_runtime.h>
#include <stdint.h>

#define NB 4
#define NC 256
#define NCI 128
#define NN 4096

typedef __attribute__((ext_vector_type(8))) short short8;
typedef __attribute__((ext_vector_type(4))) float f32x4;

__device__ __forceinline__ float bf2f(unsigned short u) {
    union { unsigned int i; float f; } v; v.i = ((unsigned int)u) << 16; return v.f;
}
__device__ __forceinline__ unsigned short f2bf(float f) {
    union { unsigned int i; float f; } v; v.f = f;
    unsigned int b = v.i;
    b += 0x7FFFu + ((b >> 16) & 1u);   // RNE
    return (unsigned short)(b >> 16);
}

// ---------------------------------------------------------------- sentinel fill
__global__ void k_fill(float* __restrict__ p, float v, int n) {
    int i = blockIdx.x * blockDim.x + threadIdx.x;
    if (i < n) p[i] = v;
}

// ---------------------------------------------------------------- K0: weight split/convert
__global__ __launch_bounds__(256) void k_split(
    const float* __restrict__ Wt, const float* __restrict__ Wp,
    const float* __restrict__ Wg, const float* __restrict__ Wo,
    unsigned short* __restrict__ wbuf) {
    const float LOG2E = 1.4426950408889634f;
    int m = blockIdx.y;
    int i = blockIdx.x * 256 + threadIdx.x;
    if (m == 0) {
        float v = Wt[i] * LOG2E;
        unsigned short h = f2bf(v);
        wbuf[i] = h;
        wbuf[32768 + i] = f2bf(v - bf2f(h));
    } else if (m == 1) {
        float v = Wp[i];
        unsigned short h = f2bf(v);
        wbuf[65536 + i] = h;
        wbuf[98304 + i] = f2bf(v - bf2f(h));
    } else if (m == 2) {
        wbuf[131072 + i] = f2bf(Wg[i]);
    } else {
        wbuf[163840 + i] = f2bf(Wo[i]);
    }
}

// ---------------------------------------------------------------- K1: phi (hi/lo) + g projections
__global__ __launch_bounds__(256, 2) void k_qkv2(
    const float* __restrict__ x,
    const unsigned short* __restrict__ WpH, const unsigned short* __restrict__ WpL,
    const unsigned short* __restrict__ WgH,
    const float* __restrict__ bp, const float* __restrict__ bg,
    unsigned short* __restrict__ phiH, unsigned short* __restrict__ phiL,
    unsigned short* __restrict__ gout) {
    __shared__ __align__(16) unsigned short sXh[32 * 72];
    __shared__ __align__(16) unsigned short sXl[32 * 72];
    const int b = blockIdx.y, n0 = blockIdx.x * 32;
    const int tid = threadIdx.x, lane = tid & 63, wave = tid >> 6;
    const int col = lane & 15, quad = lane >> 4;
    const int wm = wave * 32;

    f32x4 accP[2][2], accG[2][2];
#pragma unroll
    for (int i = 0; i < 2; i++)
#pragma unroll
        for (int j = 0; j < 2; j++)
#pragma unroll
            for (int e = 0; e < 4; e++) { accP[i][j][e] = 0.f; accG[i][j][e] = 0.f; }

    for (int c0 = 0; c0 < NC; c0 += 64) {
        __syncthreads();
        short8 ah[2][2], al[2][2], ag[2][2];
#pragma unroll
        for (int ks = 0; ks < 2; ks++)
#pragma unroll
            for (int i = 0; i < 2; i++) {
                size_t w = (size_t)(wm + i * 16 + col) * NC + c0 + ks * 32 + quad * 8;
                ah[ks][i] = *(const short8*)&WpH[w];
                al[ks][i] = *(const short8*)&WpL[w];
                ag[ks][i] = *(const short8*)&WgH[w];
            }
        {
            int cp = tid >> 3, n4 = (tid & 7) * 4;
            const float* xp = x + ((size_t)(b * NC + c0 + 2 * cp)) * NN + n0 + n4;
            float4 a = *(const float4*)xp;
            float4 c = *(const float4*)(xp + NN);
            float av[4] = { a.x, a.y, a.z, a.w };
            float cv[4] = { c.x, c.y, c.z, c.w };
#pragma unroll
            for (int j = 0; j < 4; j++) {
                unsigned short ha = f2bf(av[j]), hc = f2bf(cv[j]);
                unsigned short la = f2bf(av[j] - bf2f(ha)), lc = f2bf(cv[j] - bf2f(hc));
                *(unsigned int*)&sXh[(n4 + j) * 72 + 2 * cp] =
                    (unsigned int)ha | ((unsigned int)hc << 16);
                *(unsigned int*)&sXl[(n4 + j) * 72 + 2 * cp] =
                    (unsigned int)la | ((unsigned int)lc << 16);
            }
        }
        __syncthreads();
#pragma unroll
        for (int ks = 0; ks < 2; ks++)
#pragma unroll
            for (int j = 0; j < 2; j++) {
                short8 bh = *(const short8*)&sXh[(j * 16 + col) * 72 + ks * 32 + quad * 8];
                short8 bl = *(const short8*)&sXl[(j * 16 + col) * 72 + ks * 32 + quad * 8];
#pragma unroll
                for (int i = 0; i < 2; i++) {
                    accP[i][j] = __builtin_amdgcn_mfma_f32_16x16x32_bf16(ah[ks][i], bh, accP[i][j], 0, 0, 0);
                    accP[i][j] = __builtin_amdgcn_mfma_f32_16x16x32_bf16(ah[ks][i], bl, accP[i][j], 0, 0, 0);
                    accP[i][j] = __builtin_amdgcn_mfma_f32_16x16x32_bf16(al[ks][i], bh, accP[i][j], 0, 0, 0);
                    accG[i][j] = __builtin_amdgcn_mfma_f32_16x16x32_bf16(ag[ks][i], bh, accG[i][j], 0, 0, 0);
                }
            }
    }
#pragma unroll
    for (int i = 0; i < 2; i++) {
        int mrow = wm + i * 16 + quad * 4;
#pragma unroll
        for (int j = 0; j < 2; j++) {
            int n = n0 + j * 16 + col;
            unsigned short h[4], l[4];
#pragma unroll
            for (int e = 0; e < 4; e++) {
                float v = accP[i][j][e] + bp[mrow + e];
                h[e] = f2bf(v);
                l[e] = f2bf(v - bf2f(h[e]));
            }
            uint2 hv, lv;
            hv.x = (unsigned int)h[0] | ((unsigned int)h[1] << 16);
            hv.y = (unsigned int)h[2] | ((unsigned int)h[3] << 16);
            lv.x = (unsigned int)l[0] | ((unsigned int)l[1] << 16);
            lv.y = (unsigned int)l[2] | ((unsigned int)l[3] << 16);
            *(uint2*)&phiH[((size_t)(b * NN + n)) * NCI + mrow] = hv;
            *(uint2*)&phiL[((size_t)(b * NN + n)) * NCI + mrow] = lv;
#pragma unroll
            for (int r = 0; r < 4; r++)
                gout[((size_t)(b * NCI + mrow + r)) * NN + n] = f2bf(accG[i][j][r] + bg[mrow + r]);
        }
    }
}

// ---------------------------------------------------------------- K2: fused attention, 16 waves
// REVERT to R9 (best measured: k_attn 108 us, no spill) + ONE change: the QK
// accumulation is split into THREE independent MFMA chains (Shh=qh*ph,
// Shl=qh*pl, Slh=ql*ph; depth 4 each, summed before exp2) instead of one
// depth-12 serial chain — 12 independent streams/SIMD keeps the matrix pipe
// fed across latency. +8 VGPR (R9 at 64, ample), numerics identical
// (fp32 add reorder only). All else byte-identical to R9: 1 barrier/tile,
// 2-step unroll, G 4-slot ring via scalar XOR offsets, named-scalar staging.
__global__ __launch_bounds__(1024, 4) void k_attn(
    const float* __restrict__ x,
    const unsigned short* __restrict__ WtH, const unsigned short* __restrict__ WtL,
    const float* __restrict__ bt,
    const unsigned short* __restrict__ phiH, const unsigned short* __restrict__ phiL,
    const unsigned short* __restrict__ gmat,
    const unsigned short* __restrict__ WoH, const float* __restrict__ bo,
    float* __restrict__ y) {
    const float LOG2E = 1.4426950408889634f;
    __shared__ __align__(16) char smem[148480];
    // main-loop regions
    unsigned short* sPhiH0 = (unsigned short*)(smem);            // [64 m][128] swz
    unsigned short* sPhiH1 = (unsigned short*)(smem + 16384);
    unsigned short* sPhiL0 = (unsigned short*)(smem + 32768);
    unsigned short* sPhiL1 = (unsigned short*)(smem + 49152);
    unsigned short* sGbase = (unsigned short*)(smem + 65536);    // 4 x [128 c][64] swz
    unsigned short* sPall0 = (unsigned short*)(smem + 131072);   // [64 q][64] swz
    unsigned short* sPall1 = (unsigned short*)(smem + 139264);
    float* sLi             = (float*)(smem + 147456);            // [16 waves][16 q]
    // prologue overlays (all dead before first main-loop store)
    unsigned short* sThH  = (unsigned short*)(smem);             // [64 q][128] swz
    unsigned short* sThL  = (unsigned short*)(smem + 16384);
    unsigned short* sXhA  = (unsigned short*)(smem + 32768);     // [64 n][72] linear
    unsigned short* sXlA  = (unsigned short*)(smem + 41984);
    unsigned short* sXhB  = (unsigned short*)(smem + 51200);
    unsigned short* sXlB  = (unsigned short*)(smem + 60416);
    float* sThF           = (float*)(smem + 32768);              // [64 q][128] f32 swz (after sX dead)
    // epilogue overlay
    unsigned short* sO    = (unsigned short*)(smem);             // [64 q][128] swz

    const int id = blockIdx.x;
    const int xcd = id & 7, slot = id >> 3;                      // slot 0..31
    const int b = xcd >> 1;                                      // batch pinned to 2 XCDs
    const int n0 = (slot * 2 + (xcd & 1)) * 64;

    const int tid = threadIdx.x, lane = tid & 63, wave = tid >> 6;  // wave 0..15
    const int col = lane & 15, quad = lane >> 4;
    const int qg = wave >> 2, kh = wave & 3;

    // staged-tile registers (single set; STORET precedes LOADT in each window)
    uint4 rPh, rPl, rG;
    auto LOADT = [&](int m0) {
        int row = tid >> 4, seg = tid & 15;
        size_t src = ((size_t)(b * NN + m0 + row)) * NCI + seg * 8;
        rPh = *(const uint4*)&phiH[src];
        rPl = *(const uint4*)&phiL[src];
        int row2 = tid >> 3, seg2 = tid & 7;
        rG = *(const uint4*)&gmat[((size_t)(b * NCI + row2)) * NN + m0 + seg2 * 8];
    };
    auto STORET = [&](unsigned short* dPh, unsigned short* dPl, unsigned short* dG) {
        int row = tid >> 4, seg = tid & 15;
        int dst = row * 128 + ((seg * 8) ^ ((row & 7) << 3));
        *(uint4*)&dPh[dst] = rPh;
        *(uint4*)&dPl[dst] = rPl;
        int row2 = tid >> 3, seg2 = tid & 7;
        *(uint4*)&dG[row2 * 64 + ((seg2 * 8) ^ ((row2 & 7) << 3))] = rG;
    };

    // ---------------- prologue: theta (log2e-scaled), C-range split across halves
    const int half = wave >> 3;                 // 0: c0 in {0,64}; 1: {128,192}
    const int wci8 = (wave & 7) * 16;           // ci rows covered by this wave
    f32x4 th[4];
#pragma unroll
    for (int j = 0; j < 4; j++)
#pragma unroll
        for (int e = 0; e < 4; e++) th[j][e] = 0.f;

    for (int s = 0; s < 2; s++) {
        {   // each 512-thread half stages its own c0 chunk of x (transpose+split)
            int set = tid >> 9;                 // == wave>>3
            int t = tid & 511;
            int cp = t >> 4, n4 = (t & 15) * 4;
            int myc0 = set * 128 + s * 64;
            unsigned short* dXh = set ? sXhB : sXhA;
            unsigned short* dXl = set ? sXlB : sXlA;
            const float* xp = x + ((size_t)(b * NC + myc0 + 2 * cp)) * NN + n0 + n4;
            float4 a = *(const float4*)xp;
            float4 c = *(const float4*)(xp + NN);
            float av[4] = { a.x, a.y, a.z, a.w };
            float cv4[4] = { c.x, c.y, c.z, c.w };
#pragma unroll
            for (int j = 0; j < 4; j++) {
                unsigned short ha = f2bf(av[j]), hc = f2bf(cv4[j]);
                unsigned short la = f2bf(av[j] - bf2f(ha)), lc = f2bf(cv4[j] - bf2f(hc));
                *(unsigned int*)&dXh[(n4 + j) * 72 + 2 * cp] =
                    (unsigned int)ha | ((unsigned int)hc << 16);
                *(unsigned int*)&dXl[(n4 + j) * 72 + 2 * cp] =
                    (unsigned int)la | ((unsigned int)lc << 16);
            }
        }
        __syncthreads();
        {
            int c0 = half * 128 + s * 64;
            const unsigned short* mXh = half ? sXhB : sXhA;
            const unsigned short* mXl = half ? sXlB : sXlA;
#pragma unroll
            for (int ks = 0; ks < 2; ks++) {
                size_t w = (size_t)(wci8 + col) * NC + c0 + ks * 32 + quad * 8;
                short8 ah = *(const short8*)&WtH[w];
                short8 al = *(const short8*)&WtL[w];
#pragma unroll
                for (int j = 0; j < 4; j++) {
                    short8 bh = *(const short8*)&mXh[(j * 16 + col) * 72 + ks * 32 + quad * 8];
                    short8 bl = *(const short8*)&mXl[(j * 16 + col) * 72 + ks * 32 + quad * 8];
                    th[j] = __builtin_amdgcn_mfma_f32_16x16x32_bf16(ah, bh, th[j], 0, 0, 0);
                    th[j] = __builtin_amdgcn_mfma_f32_16x16x32_bf16(ah, bl, th[j], 0, 0, 0);
                    th[j] = __builtin_amdgcn_mfma_f32_16x16x32_bf16(al, bh, th[j], 0, 0, 0);
                }
            }
        }
        __syncthreads();
    }
    // merge halves: half 0 writes f32 partials; half 1 adds, biases, splits hi/lo
    if (half == 0) {
#pragma unroll
        for (int j = 0; j < 4; j++) {
            int q = j * 16 + col;
            int ci = (wci8 + quad * 4) ^ ((q & 7) << 2);
            *(f32x4*)&sThF[q * 128 + ci] = th[j];
        }
    }
    __syncthreads();
    if (half == 1) {
#pragma unroll
        for (int j = 0; j < 4; j++) {
            int q = j * 16 + col;
            int cif = (wci8 + quad * 4) ^ ((q & 7) << 2);
            f32x4 o = *(const f32x4*)&sThF[q * 128 + cif];
            unsigned short h[4], l[4];
#pragma unroll
            for (int e = 0; e < 4; e++) {
                float v = o[e] + th[j][e] + bt[wci8 + quad * 4 + e] * LOG2E;
                h[e] = f2bf(v);
                l[e] = f2bf(v - bf2f(h[e]));
            }
            int cisw = (wci8 + quad * 4) ^ ((q & 7) << 3);
            uint2 hv, lv;
            hv.x = (unsigned int)h[0] | ((unsigned int)h[1] << 16);
            hv.y = (unsigned int)h[2] | ((unsigned int)h[3] << 16);
            lv.x = (unsigned int)l[0] | ((unsigned int)l[1] << 16);
            lv.y = (unsigned int)l[2] | ((unsigned int)l[3] << 16);
            *(uint2*)&sThH[q * 128 + cisw] = hv;
            *(uint2*)&sThL[q * 128 + cisw] = lv;
        }
    }
    __syncthreads();
    // theta fragments for this wave's 16-query group, held for the whole kernel
    short8 qh[4], ql[4];
    {
        int qrow = qg * 16 + col;
        int qsw = (qrow & 7) << 3;
#pragma unroll
        for (int ks = 0; ks < 4; ks++) {
            int off = (ks * 32 + quad * 8) ^ qsw;
            qh[ks] = *(const short8*)&sThH[qrow * 128 + off];
            ql[ks] = *(const short8*)&sThL[qrow * 128 + off];
        }
    }
    // prestage: tile 0 -> phi[0]/G[0]; tile 1 staged into registers
    LOADT(0);
    __syncthreads();                 // all waves finished reading sThH/sThL
    STORET(sPhiH0, sPhiL0, sGbase);  // tile 0 -> phi0, G slot 0
    LOADT(64);                       // tile 1 -> regs
    __syncthreads();                 // phi0/G0 visible

    // ---------------- main K-loop: 1 barrier/tile, 2-step unroll, static phi/P
    f32x4 oacc[2];
#pragma unroll
    for (int i = 0; i < 2; i++)
#pragma unroll
        for (int e = 0; e < 4; e++) oacc[i][e] = 0.f;
    float li[4] = { 0.f, 0.f, 0.f, 0.f };      // per-lane partial (this col's keys)

    auto step = [&](const unsigned short* cPhiH, const unsigned short* cPhiL,
                    unsigned short* nPhiH, unsigned short* nPhiL,
                    unsigned short* wG, const unsigned short* rGb,
                    unsigned short* wPall, const unsigned short* rPall,
                    int m_next, bool do_pv) {
        STORET(nPhiH, nPhiL, wG);
        LOADT(m_next);

        // QK(t): 16 queries (regs) x this wave's 16-key quarter.
        // THREE independent accumulator chains (depth 4 each) instead of one
        // depth-12 chain -> matrix pipe stays fed across MFMA latency.
        f32x4 Sa, Sb, Sc;
#pragma unroll
        for (int e = 0; e < 4; e++) { Sa[e] = 0.f; Sb[e] = 0.f; Sc[e] = 0.f; }
        {
            int kcol = kh * 16 + col;
            int kswz = (kcol & 7) << 3;
#pragma unroll
            for (int ks = 0; ks < 4; ks++) {
                int off = (ks * 32 + quad * 8) ^ kswz;
                short8 ph = *(const short8*)&cPhiH[kcol * 128 + off];
                short8 pl = *(const short8*)&cPhiL[kcol * 128 + off];
                Sa = __builtin_amdgcn_mfma_f32_16x16x32_bf16(qh[ks], ph, Sa, 0, 0, 0);
                Sb = __builtin_amdgcn_mfma_f32_16x16x32_bf16(qh[ks], pl, Sb, 0, 0, 0);
                Sc = __builtin_amdgcn_mfma_f32_16x16x32_bf16(ql[ks], ph, Sc, 0, 0, 0);
            }
        }
        // PV(t-1): independent MFMAs fill the QK->exp2 dependency shadow
        if (do_pv) {
            short8 pf[2], af[2][2];
            int qrow = qg * 16 + col;
            int qsw = (qrow & 7) << 3;
#pragma unroll
            for (int ks = 0; ks < 2; ks++)
                pf[ks] = *(const short8*)&rPall[qrow * 64 + ((ks * 32 + quad * 8) ^ qsw)];
#pragma unroll
            for (int ct = 0; ct < 2; ct++) {
                int grow = kh * 32 + ct * 16 + col;
                int gsw = (grow & 7) << 3;
#pragma unroll
                for (int ks = 0; ks < 2; ks++)
                    af[ct][ks] = *(const short8*)&rGb[grow * 64 + ((ks * 32 + quad * 8) ^ gsw)];
            }
#pragma unroll
            for (int ct = 0; ct < 2; ct++)
#pragma unroll
                for (int ks = 0; ks < 2; ks++)
                    oacc[ct] = __builtin_amdgcn_mfma_f32_16x16x32_bf16(
                        af[ct][ks], pf[ks], oacc[ct], 0, 0, 0);
        }
        // softmax(t): per-lane li accumulation, P write swizzled
#pragma unroll
        for (int r = 0; r < 4; r++) {
            float p = exp2f(Sa[r] + Sb[r] + Sc[r]);
            li[r] += p;
            int q = qg * 16 + quad * 4 + r;
            wPall[q * 64 + ((kh * 16 + col) ^ ((q & 7) << 3))] = f2bf(p);
        }
        __syncthreads();             // single barrier per tile
    };

    // G slot offsets in shorts (slot k = k*8192). Step A = even t, B = odd t.
    int gwA = 8192, grA = 24576, gwB = 16384, grB = 0;
    for (int it = 0; it < 32; ++it) {
        int mA = it * 128 + 128; if (mA > 4032) mA = 4032;   // tile t+2 (clamped tail)
        int mB = it * 128 + 192; if (mB > 4032) mB = 4032;
        step(sPhiH0, sPhiL0, sPhiH1, sPhiL1, sGbase + gwA, sGbase + grA,
             sPall0, sPall1, mA, it != 0);
        step(sPhiH1, sPhiL1, sPhiH0, sPhiL0, sGbase + gwB, sGbase + grB,
             sPall1, sPall0, mB, true);
        gwA ^= 16384; grA ^= 16384; gwB ^= 16384; grB ^= 16384;
    }
    // final PV(63): P in pall[1], G in slot 63%4 = 3 (static)
    {
        short8 pf[2], af[2][2];
        int qrow = qg * 16 + col;
        int qsw = (qrow & 7) << 3;
#pragma unroll
        for (int ks = 0; ks < 2; ks++)
            pf[ks] = *(const short8*)&sPall1[qrow * 64 + ((ks * 32 + quad * 8) ^ qsw)];
#pragma unroll
        for (int ct = 0; ct < 2; ct++) {
            int grow = kh * 32 + ct * 16 + col;
            int gsw = (grow & 7) << 3;
#pragma unroll
            for (int ks = 0; ks < 2; ks++)
                af[ct][ks] = *(const short8*)&sGbase[24576 + grow * 64 + ((ks * 32 + quad * 8) ^ gsw)];
        }
#pragma unroll
        for (int ct = 0; ct < 2; ct++)
#pragma unroll
            for (int ks = 0; ks < 2; ks++)
                oacc[ct] = __builtin_amdgcn_mfma_f32_16x16x32_bf16(
                    af[ct][ks], pf[ks], oacc[ct], 0, 0, 0);
    }

    // ---------------- li: one wave-level reduce over the 16 cols, then merge kh
#pragma unroll
    for (int r = 0; r < 4; r++) {
        float rs = li[r];
#pragma unroll
        for (int off = 1; off < 16; off <<= 1) rs += __shfl_xor(rs, off);
        li[r] = rs;
    }
    if (col == 0) {
#pragma unroll
        for (int r = 0; r < 4; r++) sLi[wave * 16 + quad * 4 + r] = li[r];
    }
    __syncthreads();
    float inv = 1.0f / (sLi[(qg * 4 + 0) * 16 + col] + sLi[(qg * 4 + 1) * 16 + col] +
                        sLi[(qg * 4 + 2) * 16 + col] + sLi[(qg * 4 + 3) * 16 + col]);

    // O -> LDS (bf16, swizzled), overlays dead phi0
#pragma unroll
    for (int ct = 0; ct < 2; ct++) {
        int q = qg * 16 + col;
        int ci = kh * 32 + ct * 16 + quad * 4;
        int cisw = ci ^ ((q & 7) << 3);
        uint2 v;
        unsigned short p0 = f2bf(oacc[ct][0] * inv);
        unsigned short p1 = f2bf(oacc[ct][1] * inv);
        unsigned short p2 = f2bf(oacc[ct][2] * inv);
        unsigned short p3 = f2bf(oacc[ct][3] * inv);
        v.x = (unsigned int)p0 | ((unsigned int)p1 << 16);
        v.y = (unsigned int)p2 | ((unsigned int)p3 << 16);
        *(uint2*)&sO[q * 128 + cisw] = v;
    }
    __syncthreads();
    // out-proj: wave's 16-o tile + bias + residual; Wo A-frags straight from global
    f32x4 acc[4];
#pragma unroll
    for (int j = 0; j < 4; j++)
#pragma unroll
        for (int e = 0; e < 4; e++) acc[j][e] = 0.f;
#pragma unroll
    for (int ks = 0; ks < 4; ks++) {
        short8 af2 = *(const short8*)&WoH[(size_t)(wave * 16 + col) * NCI + ks * 32 + quad * 8];
#pragma unroll
        for (int j = 0; j < 4; j++) {
            int row = j * 16 + col;
            short8 bf = *(const short8*)&sO[row * 128 + ((ks * 32 + quad * 8) ^ ((row & 7) << 3))];
            acc[j] = __builtin_amdgcn_mfma_f32_16x16x32_bf16(af2, bf, acc[j], 0, 0, 0);
        }
    }
#pragma unroll
    for (int j = 0; j < 4; j++)
#pragma unroll
        for (int e = 0; e < 4; e++) {
            int o = wave * 16 + quad * 4 + e;
            size_t idx = ((size_t)(b * NC + o)) * NN + n0 + j * 16 + col;
            y[idx] = acc[j][e] + bo[o] + x[idx];
        }
}

// ---------------------------------------------------------------- launch
extern "C" void kernel_launch(void* const* d_in, const int* in_sizes, int n_in,
                              void* d_out, int out_size, void* d_ws, size_t ws_size,
                              hipStream_t stream) {
    float* y = (float*)d_out;

    bool sizes_ok = (n_in == 9) &&
        in_sizes[0] == NB * NC * NN && in_sizes[1] == NCI * NC && in_sizes[2] == NCI &&
        in_sizes[3] == NCI * NC && in_sizes[4] == NCI && in_sizes[5] == NCI * NC &&
        in_sizes[6] == NCI && in_sizes[7] == NC * NCI && in_sizes[8] == NC &&
        out_size == NB * NC * NN;
    if (!sizes_ok) {
        k_fill<<<(out_size + 255) / 256, 256, 0, stream>>>(y, 777.0f, out_size);
        return;
    }
    if (ws_size < (size_t)16 * 1024 * 1024) {
        k_fill<<<(out_size + 255) / 256, 256, 0, stream>>>(y, 555.0f, out_size);
        return;
    }

    const float* x  = (const float*)d_in[0];
    const float* tw = (const float*)d_in[1];
    const float* tb = (const float*)d_in[2];
    const float* pw = (const float*)d_in[3];
    const float* pb = (const float*)d_in[4];
    const float* gw = (const float*)d_in[5];
    const float* gb = (const float*)d_in[6];
    const float* ow = (const float*)d_in[7];
    const float* obias = (const float*)d_in[8];

    unsigned short* ws16 = (unsigned short*)d_ws;
    unsigned short* phiH = ws16;                 // [B][N][Ci] bf16 hi
    unsigned short* phiL = ws16 + 2097152;       // [B][N][Ci] bf16 lo
    unsigned short* g    = ws16 + 4194304;       // [B][Ci][N] bf16
    unsigned short* wbuf = ws16 + 6291456;       // WtH,WtL,WpH,WpL,WgH,WoH
    unsigned short* WtH = wbuf,           *WtL = wbuf + 32768;
    unsigned short* WpH = wbuf + 65536,   *WpL = wbuf + 98304;
    unsigned short* WgH = wbuf + 131072,  *WoH = wbuf + 163840;

    k_split<<<dim3(128, 4), 256, 0, stream>>>(tw, pw, gw, ow, wbuf);
    k_qkv2<<<dim3(128, NB), 256, 0, stream>>>(x, WpH, WpL, WgH, pb, gb, phiH, phiL, g);
    k_attn<<<dim3(256), 1024, 0, stream>>>(x, WtH, WtL, tb, phiH, phiL, g, WoH, obias, y);
}